// Round 8
// baseline (259.340 us; speedup 1.0000x reference)
//
#include <hip/hip_runtime.h>
#include <cmath>
#include <cstdint>
#include <vector>
#include <cstdlib>
#include <algorithm>

#define WGB 256

typedef float vf4 __attribute__((ext_vector_type(4)));   // native vector: OK for nontemporal builtins

// ---------------- constexpr problem metadata (evaluated identically host+device) ----------------
struct TripleMeta { int l,l1,l2,d,d1,d2,form,dp4,cgR,cgL,uv; };
struct AllMeta { TripleMeta t[48]; int nT, cgTotal, uvTotal; };

constexpr AllMeta build_meta() {
  AllMeta M{};
  const int LSl[5] = {0,2,4,6,8};
  int k=0, cg=0;
  for (int a=0;a<5;a++){ const int l=LSl[a];
    for (int b=0;b<5;b++){ const int l1=LSl[b];
      for (int l2=l1;l2<=8;l2+=2){
        if (!((l2-l1)<=l && l<=(l1+l2))) continue;
        TripleMeta m{};
        m.l=l; m.l1=l1; m.l2=l2;
        m.d=2*l+1; m.d1=2*l1+1; m.d2=2*l2+1;
        m.form = (l1==0) ? ((l2==0)?2:1) : 0;   // 0=A (l1>0), 1=B (l1==0,l2>0), 2=D (0,0,0)
        m.dp4 = ((m.d+3)/4)*4;
        m.cgR = cg; cg += m.d*m.d1*m.d2;
        M.t[k] = m; k++;
      } } }
  M.nT=k; M.cgTotal=cg;
  int cgl=cg;
  for (int i=0;i<k;i++){ M.t[i].cgL=cgl; cgl += M.t[i].d*M.t[i].d1*M.t[i].d2; }
  int uv=0;
  for (int i=0;i<k;i++){
    if (M.t[i].form==0){ M.t[i].uv=uv; uv += 4*M.t[i].dp4; }
    else if (M.t[i].form==1){ M.t[i].uv=uv; uv += 2*M.t[i].dp4; }
  }
  M.uvTotal=uv;
  return M;
}

constexpr AllMeta META_H = build_meta();            // host view
static_assert(META_H.nT==42, "nT");
static_assert(META_H.cgTotal==52334, "cgTotal");
static_assert(META_H.uvTotal==2048, "uvTotal");

__device__ constexpr AllMeta META = build_meta();   // device view (identical values)

constexpr int CG_TOTAL  = 52334;
constexpr int UVS       = 2048;      // U/V slot-table stride (floats)
constexpr int ZTOT      = 4520;      // z-buffer floats in LDS (8*d^2 summed, one voxel)
constexpr int XBS       = 104;       // per-voxel xb stride in LDS
constexpr int WI_N      = 512;       // padded U work-item table: 8 wave-passes x 64 lanes

constexpr int T0G_H[6]  = {0,5,13,23,33,42};

// number of (triple,pr) V slots per output-l group (compile-time; li: 16/30/38/38/34)
constexpr int NV_OF(int LI){
  int n=0;
  for (int t=T0G_H[LI]; t<T0G_H[LI+1]; t++){
    if (META_H.t[t].form==0) n+=4;
    else if (META_H.t[t].form==1) n+=2;
  }
  return n;
}

__device__ constexpr int DL[5]     = {1,5,9,13,17};
__device__ constexpr int T0G[6]    = {0,5,13,23,33,42};       // triple ranges per output-l group
__device__ constexpr int RHNB[5]   = {163840,196608,1015808,3670016,9207808}; // rh_n out offsets
__device__ constexpr int CBASE[5]  = {352,312,240,136,0};     // fpart base per li (li4 first)
__device__ constexpr int LEN5[5]   = {8,200,648,1352,2312};   // 8*d^2 per voxel
// z-buffer: per-li base, 8*d^2 each; all %4==0 for float4 copy
__device__ constexpr int ZB[5]     = {0,8,208,856,2208};
__device__ constexpr int C4[6]     = {0,2,52,214,552,1130};   // cumulative float4 counts

// phase-3 static PER-VOXEL wave schedule: li-pure passes {li, col_base, col_end},
// col-space per li = 8c*d = {8,40,72,104,136}. Per-pass wave cost (scalar-FMA issue
// units): li4=680 li3=608 li2=456 li1=240 li0=68. Wave totals: 1136/1136/988/1216
// (ideal 1119). No mixed-li divergence inside a pass.
__device__ constexpr int SCHEDV[4][3][3] = {
  {{4,  0, 46},{2,  0, 36},{-1,0,0}},
  {{4, 46, 91},{2, 36, 72},{-1,0,0}},
  {{4, 91,136},{1,  0, 40},{ 0,0,8}},
  {{3,  0, 52},{3, 52,104},{-1,0,0}},
};

// ---------------- kernel 1: V table — one block per (triple, abc), CG slab staged in LDS ----------------
// (R0's 1344-block form: measured rest ≈ 87-91us vs 138us for the 84-block variant — R0/R3 vs R1/R2)
// V_{t,p,q}[k2] = sum_a wA[p,a] * sum_j wB[q,j] * R_t[k2,a,j]
__global__ __launch_bounds__(128) void s2_prep(
    const float* __restrict__ w2, const float* __restrict__ w4,
    const float* __restrict__ w6, const float* __restrict__ w8,
    const float* __restrict__ cg, float* __restrict__ V)
{
  __shared__ float Rs[4928];           // max d*d1*d2 = 17*17*17 = 4913
  const int bid = blockIdx.x;
  const int t   = bid >> 5;
  const int abc = bid & 31;
  const auto &m = META.t[t];
  if (m.form == 2) return;             // (0,0,0) handled analytically in s2_main
  const int ab = abc >> 3, c = abc & 7;
  const int sz = m.d * m.d1 * m.d2;
  for (int i = threadIdx.x; i < sz; i += 128) Rs[i] = cg[m.cgR + i];   // coalesced
  __syncthreads();
  const float* ws[4] = {w2,w4,w6,w8};
  const int nout = (m.form==0 ? 4 : 2) * m.d;
  if ((int)threadIdx.x < nout){
    const int pq = threadIdx.x / m.d;
    const int k2 = threadIdx.x - pq*m.d;
    float s = 0.f;
    if (m.form==0){
      const int p = pq>>1, q = pq&1;
      const float* wA = ws[(m.l1>>1)-1] + ((ab*2+p)*8 + c)*m.d1;
      const float* wB = ws[(m.l2>>1)-1] + ((ab*2+q)*8 + c)*m.d2;
      const float* Rk = Rs + k2*m.d1*m.d2;
      for (int a=0;a<m.d1;a++){
        float t2 = 0.f;
        for (int j=0;j<m.d2;j++) t2 += wB[j]*Rk[a*m.d2+j];
        s += wA[a]*t2;
      }
    } else {
      const float* wB = ws[(m.l2>>1)-1] + ((ab*2+pq)*8 + c)*m.d2;
      const float* Rk = Rs + k2*m.d2;   // d1==1
      for (int j=0;j<m.d2;j++) s += wB[j]*Rk[j];
    }
    V[abc*UVS + m.uv + pq*m.dp4 + k2] = s;
  }
}

// ---------------- fused phase 1+2, G=2 voxels: one (t,k1) item -> 8 (or 4) U values ----------------
template<int D1>
__device__ __forceinline__ void u_itemA(const float* __restrict__ Lp, const float* xb,
    float* Ush, int dst, int dstr, int xo1, int xo2, int d2)
{
  float x0r[2*D1], x1r[2*D1];
  #pragma unroll
  for (int j=0;j<2*D1;j++){ x0r[j] = xb[xo1+j]; x1r[j] = xb[XBS+xo1+j]; }
  float a00=0.f,a01=0.f,a10=0.f,a11=0.f;
  float b00=0.f,b01=0.f,b10=0.f,b11=0.f;
  for (int b=0;b<d2;b++){
    float i00=0.f, i01=0.f, i10=0.f, i11=0.f;     // i{voxel}{p}
    const float* Lb = Lp + b*D1;                   // contiguous slab: 8 FMAs per CG load
    #pragma unroll
    for (int j=0;j<D1;j++){
      const float lv=Lb[j];
      i00+=lv*x0r[j]; i01+=lv*x0r[D1+j];
      i10+=lv*x1r[j]; i11+=lv*x1r[D1+j];
    }
    const float q00=xb[xo2+b],     q01=xb[xo2+d2+b];
    const float q10=xb[XBS+xo2+b], q11=xb[XBS+xo2+d2+b];
    a00+=q00*i00; a01+=q01*i00; a10+=q00*i01; a11+=q01*i01;
    b00+=q10*i10; b01+=q11*i10; b10+=q10*i11; b11+=q11*i11;
  }
  Ush[dst]=a00; Ush[dst+dstr]=a01; Ush[dst+2*dstr]=a10; Ush[dst+3*dstr]=a11;
  Ush[UVS+dst]=b00; Ush[UVS+dst+dstr]=b01; Ush[UVS+dst+2*dstr]=b10; Ush[UVS+dst+3*dstr]=b11;
}

__device__ __forceinline__ void u_item(const int4 w, const float* __restrict__ cg,
                                       const float* xb, float* Ush)
{
  if (w.z == 0) return;                 // idle-lane sentinel (real items have d2 field >= 5)
  const float* Lp = cg + w.x;
  const int dst = w.y & 0xFFFF, dstr = ((unsigned)w.y) >> 16;
  const int xo1 = w.z & 0xFF, xo2 = (w.z>>8)&0xFF;
  const int d1 = (w.z>>16)&0x3F, d2 = ((unsigned)w.z)>>22;
  if (d1 == 0){                         // FormB: U'[q][k1] = sum_b L[k1,b]*x2[q,b]
    float a0=0.f, a1=0.f, b0=0.f, b1=0.f;
    for (int b=0;b<d2;b++){
      const float lv=Lp[b];
      a0+=lv*xb[xo2+b];     a1+=lv*xb[xo2+d2+b];
      b0+=lv*xb[XBS+xo2+b]; b1+=lv*xb[XBS+xo2+d2+b];
    }
    Ush[dst]=a0; Ush[dst+dstr]=a1;
    Ush[UVS+dst]=b0; Ush[UVS+dst+dstr]=b1;
    return;
  }
  switch(d1){
    case 5:  u_itemA<5>(Lp,xb,Ush,dst,dstr,xo1,xo2,d2); break;
    case 9:  u_itemA<9>(Lp,xb,Ush,dst,dstr,xo1,xo2,d2); break;
    case 13: u_itemA<13>(Lp,xb,Ush,dst,dstr,xo1,xo2,d2); break;
    default: u_itemA<17>(Lp,xb,Ush,dst,dstr,xo1,xo2,d2); break;
  }
}

// ---------------- phase-3 column worker (one (c, l, k2) column) -> z into LDS ----------------
// Two-phase form: (a) batch-issue ALL NV independent V scalar loads into registers (one
// latency exposure, loads stream from L2), then (b) FMA sweep with wave-uniform float4
// LDS broadcasts of U. Replaces the load->use->load->use chain whose s_waitcnt before each
// FMA group blocked the next load from issuing (in-order wave) — the R2/R7 48%-idle stall.
template<int LI>
__device__ __forceinline__ float col_work(int k2, float rh0c, float c000,
    const float* __restrict__ Vc, const float* Ush,
    float* zsh, int zb)
{
  constexpr int d   = 4*LI + 1;
  constexpr int np4 = (d+3)/4;
  constexpr int NV  = NV_OF(LI);     // 16/30/38/38/34 — vv[] fully unrolled -> registers
  const float* __restrict__ Vck = Vc + k2;
  float vv[NV];
  {
    int vi = 0;
    #pragma unroll
    for (int t=T0G[LI]; t<T0G[LI+1]; t++){
      const auto &m = META.t[t];
      if (m.form==2) continue;
      const int npr = (m.form==0)?4:2;
      #pragma unroll
      for (int pr=0;pr<npr;pr++)
        vv[vi++] = Vck[m.uv + pr*m.dp4];     // constant offsets off one base: batched issue
    }
  }
  float4 za[np4];
  #pragma unroll
  for (int i=0;i<np4;i++) za[i] = make_float4(0.f,0.f,0.f,0.f);
  {
    int vi = 0;
    #pragma unroll
    for (int t=T0G[LI]; t<T0G[LI+1]; t++){
      const auto &m = META.t[t];
      if (m.form==2){
        za[0].x += rh0c*rh0c*c000;
        continue;
      }
      const int npr = (m.form==0)?4:2;
      #pragma unroll
      for (int pr=0;pr<npr;pr++){
        float v = vv[vi++];
        if (m.form==1) v *= rh0c;
        const float4* Up = reinterpret_cast<const float4*>(Ush + m.uv + pr*m.dp4);
        #pragma unroll
        for (int rr=0;rr<np4;rr++){
          float4 u = Up[rr];           // wave-uniform LDS broadcast
          za[rr].x += u.x*v; za[rr].y += u.y*v; za[rr].z += u.z*v; za[rr].w += u.w*v;
        }
      }
    }
  }
  float s = 0.f;
  #pragma unroll
  for (int rr=0;rr<np4;rr++){
    const float vals[4] = {za[rr].x, za[rr].y, za[rr].z, za[rr].w};
    #pragma unroll
    for (int e=0;e<4;e++){
      const int k1 = 4*rr+e;
      if (k1 < d){
        zsh[zb + k1*d + k2] = vals[e];   // LDS scatter (d odd -> conflict-light); global is ph3b
        s += vals[e]*vals[e];
      }
    }
  }
  return s;
}

// one li-pure pass for one voxel: lane -> (c,k2) column within [base,end)
template<int LI>
__device__ __forceinline__ void do_passv(int base, int end, int lane, int v,
    const float* __restrict__ Vab, const float* Ush, const float* rh0s,
    float* zsh, float* fpart, float c000)
{
  constexpr int d = 4*LI + 1;
  const int col = base + lane;
  if (col >= end) return;
  const int c  = col / d;               // constexpr d -> magic mul
  const int k2 = col - c*d;
  const float s = col_work<LI>(k2, rh0s[v*8+c], c000, Vab + c*UVS, Ush + v*UVS,
                               zsh, ZB[LI] + c*d*d);
  fpart[CBASE[LI] + col] = s;
}

// ---------------- kernel 2: main, one block per 2 voxels ----------------
__global__ __launch_bounds__(WGB,4) void s2_main(
    const float* __restrict__ x0, const float* __restrict__ x2, const float* __restrict__ x4,
    const float* __restrict__ x6, const float* __restrict__ x8,
    const float* __restrict__ w0, const float* __restrict__ bias,
    const float* __restrict__ cg, const int4* __restrict__ wiU,
    const float* __restrict__ V, float* __restrict__ out, float c000)
{
  __shared__ alignas(16) float SH[ZTOT + 2*UVS];   // [z (1 voxel) | U(v0) | U(v1)]
  __shared__ float xb[2*XBS];
  __shared__ float rh0s[16];
  __shared__ float fpart[360];
  float* const Ush = SH + ZTOT;
  const int tid = threadIdx.x;
  const int bid = blockIdx.x;
  const int ab  = bid >> 9;            // vox = bid*2+v; both voxels share ab

  // ---- phase 0: stage x for 2 voxels (half-block each), compute rh0 ----
  {
    const int v  = tid >> 7;           // 0 or 1
    const int t2 = tid & 127;
    const int vox = bid*2 + v;
    float* xv = xb + v*XBS;
    if (t2 < 5)        xv[t2]           = x0[vox*5  + t2];
    else if (t2 < 15)  xv[8  + (t2-5)]  = x2[vox*10 + (t2-5)];
    else if (t2 < 33)  xv[18 + (t2-15)] = x4[vox*18 + (t2-15)];
    else if (t2 < 59)  xv[36 + (t2-33)] = x6[vox*26 + (t2-33)];
    else if (t2 < 93)  xv[62 + (t2-59)] = x8[vox*34 + (t2-59)];
    else if (t2 >= 96 && t2 < 104) {
      const int c = t2 - 96;
      float s = bias[ab*8 + c];
      for (int i=0;i<5;i++) s += x0[vox*5+i] * w0[(ab*5+i)*8 + c];
      rh0s[v*8 + c] = s;
    }
  }
  __syncthreads();

  // ---- phase 1+2 fused: d1-pure LPT-balanced wave passes (2 per wave) ----
  #pragma unroll 1
  for (int it=0; it<2; it++) u_item(wiU[it*WGB + tid], cg, xb, Ush);
  __syncthreads();

  // ---- phases 3/3b/4 per voxel, z buffer reused ----
  const float* Vab = V + (ab*8)*UVS;
  const int wid = tid>>6, lane = tid&63;
  #pragma unroll 1
  for (int v=0; v<2; v++){
    const int bid2 = bid*2 + v;
    #pragma unroll 1
    for (int pi=0; pi<3; pi++){
      const int li = SCHEDV[wid][pi][0];
      if (li < 0) break;
      const int base = SCHEDV[wid][pi][1], end = SCHEDV[wid][pi][2];
      switch(li){
        case 4:  do_passv<4>(base,end,lane,v,Vab,Ush,rh0s,SH,fpart,c000); break;
        case 3:  do_passv<3>(base,end,lane,v,Vab,Ush,rh0s,SH,fpart,c000); break;
        case 2:  do_passv<2>(base,end,lane,v,Vab,Ush,rh0s,SH,fpart,c000); break;
        case 1:  do_passv<1>(base,end,lane,v,Vab,Ush,rh0s,SH,fpart,c000); break;
        default: do_passv<0>(base,end,lane,v,Vab,Ush,rh0s,SH,fpart,c000); break;
      }
    }
    __syncthreads();

    // phase 3b: coalesced vf4 nt copy LDS z -> global rh_n (full lines per wave instruction:
    // the ONLY safe nt-store shape — partial-line nt/direct scatter cost 5-18x HBM, R1/R3)
    for (int i4 = tid; i4 < 1130; i4 += WGB){
      int li;
      if      (i4 < C4[1]) li = 0;
      else if (i4 < C4[2]) li = 1;
      else if (i4 < C4[3]) li = 2;
      else if (i4 < C4[4]) li = 3;
      else                 li = 4;
      const int r4 = i4 - C4[li];
      const vf4 zv = *reinterpret_cast<const vf4*>(SH + ZB[li] + 4*r4);
      __builtin_nontemporal_store(zv, reinterpret_cast<vf4*>(out + RHNB[li] + bid2*LEN5[li] + 4*r4));
    }

    // phase 4: feats reduce: n_l * sum z^2, layout (A,B, 5*N*C)
    if (tid < 40){
      const int li = tid >> 3, c = tid & 7;
      const int d = DL[li];
      float s = 0.f;
      for (int k2=0;k2<d;k2++) s += fpart[CBASE[li] + c*d + k2];
      const double nl_d = 8.0*3.14159265358979323846*3.14159265358979323846/(double)(2*(2*li)+1);
      const int n = bid2 & 1023;
      __builtin_nontemporal_store((float)nl_d * s, out + ab*40960 + li*8192 + n*8 + c);
    }
    if (v==0) __syncthreads();   // protect z/fpart before next voxel overwrites
  }
}

// ---------------- host: numpy MT19937 + legacy gauss, tables + CG upload at dlopen ----------------
namespace {

struct MTRng {
  uint32_t mt[624]; int mti;
  bool has_g; double g;
  void seed(uint32_t s){
    for (int pos=0; pos<624; pos++){ mt[pos]=s; s = 1812433253u*(s^(s>>30)) + (uint32_t)pos + 1u; }
    mti = 624; has_g=false; g=0.0;
  }
  uint32_t next32(){
    if (mti >= 624){
      for (int i=0;i<624;i++){
        uint32_t y = (mt[i]&0x80000000u) | (mt[(i+1)%624]&0x7fffffffu);
        mt[i] = mt[(i+397)%624] ^ (y>>1) ^ ((y&1u) ? 0x9908b0dfu : 0u);
      }
      mti = 0;
    }
    uint32_t y = mt[mti++];
    y ^= y>>11; y ^= (y<<7)&0x9d2c5680u; y ^= (y<<15)&0xefc60000u; y ^= y>>18;
    return y;
  }
  double rk_double(){
    uint32_t a = next32()>>5, b = next32()>>6;
    return (a*67108864.0 + b)/9007199254740992.0;
  }
  double gauss(){
    if (has_g){ has_g=false; return g; }
    double f,x1,x2,r2;
    do {
      x1 = 2.0*rk_double()-1.0;
      x2 = 2.0*rk_double()-1.0;
      r2 = x1*x1 + x2*x2;
    } while (r2 >= 1.0 || r2 == 0.0);
    f = std::sqrt(-2.0*std::log(r2)/r2);
    g = f*x1; has_g = true;
    return f*x2;
  }
};

constexpr int XOFS_H[5] = {0,8,18,36,62};

struct DeviceSetup {
  float* d_cg  = nullptr;   // [CG_R | CG_L]  (2*CG_TOTAL floats)
  float* d_v   = nullptr;   // 32 * UVS floats, rewritten by s2_prep every launch
  int4*  d_wiU = nullptr;   // WI_N padded items
  float  c000  = 0.f;
  DeviceSetup(){
    // CG tables, bit-faithful numpy RandomState(42)
    std::vector<float> h(2*CG_TOTAL);
    MTRng r; r.seed(42u);
    for (int i=0;i<2*CG_TOTAL;i++) h[i] = (float)(r.gauss()*0.1);
    c000 = h[META_H.t[0].cgL] * h[META_H.t[0].cgR];

    // fused U work items, grouped by d1 (wave-pure passes), d2-desc within group
    struct HItem { int d2; int4 e; };
    std::vector<HItem> grp[5];   // 0..3: FormA d1=5/9/13/17 ; 4: FormB
    for (int t=0;t<META_H.nT;t++){
      const TripleMeta &m = META_H.t[t];
      if (m.form==0){
        const int xo1 = XOFS_H[m.l1>>1], xo2 = XOFS_H[m.l2>>1];
        for (int k1=0;k1<m.d;k1++){
          int4 e;
          e.x = m.cgL + k1*m.d1*m.d2;
          e.y = (m.uv + k1) | (m.dp4<<16);
          e.z = xo1 | (xo2<<8) | (m.d1<<16) | (m.d2<<22);
          e.w = 0;
          grp[(m.l1>>1)-1].push_back({m.d2, e});
        }
      } else if (m.form==1){
        const int xo2 = XOFS_H[m.l2>>1];
        for (int k1=0;k1<m.d;k1++){
          int4 e;
          e.x = m.cgL + k1*m.d2;
          e.y = (m.uv + k1) | (m.dp4<<16);
          e.z = (xo2<<8) | (0<<16) | (m.d2<<22);
          e.w = 0;
          grp[4].push_back({m.d2, e});
        }
      }
    }
    if (grp[0].size()!=111 || grp[1].size()!=128 || grp[2].size()!=89 ||
        grp[3].size()!=45  || grp[4].size()!=44) std::abort();
    for (int g=0; g<5; g++)
      std::stable_sort(grp[g].begin(), grp[g].end(),
                       [](const HItem&a, const HItem&b){ return a.d2 > b.d2; });

    // LPT layout onto 8 wave-passes (iter*256 + wave*64 + lane), sentinel {0,0,0,0}:
    // iter0: w0=d1x17(45)  w1=d1x13[0:64]  w2=d1x13[64:89]  w3=d1x9[0:64]
    // iter1: w0=FormB(44)  w1=d1x5[64:111] w2=d1x9[64:128]  w3=d1x5[0:64]
    // wave issue-cost: 1360 / 1384 / 1352 / 1224 (ideal 1330)
    int4 zero; zero.x=0; zero.y=0; zero.z=0; zero.w=0;
    std::vector<int4> wiU(WI_N, zero);
    auto place = [&](int iter, int w, const std::vector<HItem>& g, int s, int n){
      for (int i=0;i<n;i++) wiU[iter*256 + w*64 + i] = g[s+i].e;
    };
    place(0,0,grp[3],0,45);
    place(0,1,grp[2],0,64);
    place(0,2,grp[2],64,25);
    place(0,3,grp[1],0,64);
    place(1,0,grp[4],0,44);
    place(1,1,grp[0],64,47);
    place(1,2,grp[1],64,64);
    place(1,3,grp[0],0,64);

    (void)hipMalloc((void**)&d_cg,  sizeof(float)*2*CG_TOTAL);
    (void)hipMalloc((void**)&d_v,   sizeof(float)*32*UVS);
    (void)hipMalloc((void**)&d_wiU, sizeof(int4)*WI_N);
    (void)hipMemcpy(d_cg,  h.data(),    sizeof(float)*2*CG_TOTAL, hipMemcpyHostToDevice);
    (void)hipMemcpy(d_wiU, wiU.data(),  sizeof(int4)*WI_N,  hipMemcpyHostToDevice);
  }
};
DeviceSetup g_dev;   // static init at dlopen: pure-CPU RNG + one-time uploads (outside graph capture)

} // namespace

extern "C" void kernel_launch(void* const* d_in, const int* in_sizes, int n_in,
                              void* d_out, int out_size, void* d_ws, size_t ws_size,
                              hipStream_t stream)
{
  (void)in_sizes; (void)n_in; (void)d_ws; (void)ws_size; (void)out_size;
  const float* x0   = (const float*)d_in[0];
  const float* w0   = (const float*)d_in[1];
  const float* x2   = (const float*)d_in[2];
  const float* w2   = (const float*)d_in[3];
  const float* x4   = (const float*)d_in[4];
  const float* w4   = (const float*)d_in[5];
  const float* x6   = (const float*)d_in[6];
  const float* w6   = (const float*)d_in[7];
  const float* x8   = (const float*)d_in[8];
  const float* w8   = (const float*)d_in[9];
  const float* bias = (const float*)d_in[10];
  float* out = (float*)d_out;

  s2_prep<<<dim3(42*32), dim3(128), 0, stream>>>(w2,w4,w6,w8, g_dev.d_cg, g_dev.d_v);
  s2_main<<<dim3(2048), dim3(WGB), 0, stream>>>(x0,x2,x4,x6,x8, w0, bias,
                                                g_dev.d_cg, g_dev.d_wiU,
                                                g_dev.d_v, out, g_dev.c000);
}

// Round 9
// 252.321 us; speedup vs baseline: 1.0278x; 1.0278x over previous
//
#include <hip/hip_runtime.h>
#include <cmath>
#include <cstdint>
#include <vector>
#include <cstdlib>
#include <algorithm>

#define WGB 256

typedef float vf4 __attribute__((ext_vector_type(4)));   // native vector: OK for nontemporal builtins

// ---------------- constexpr problem metadata (evaluated identically host+device) ----------------
struct TripleMeta { int l,l1,l2,d,d1,d2,form,dp4,cgR,cgL,uv; };
struct AllMeta { TripleMeta t[48]; int nT, cgTotal, uvTotal; };

constexpr AllMeta build_meta() {
  AllMeta M{};
  const int LSl[5] = {0,2,4,6,8};
  int k=0, cg=0;
  for (int a=0;a<5;a++){ const int l=LSl[a];
    for (int b=0;b<5;b++){ const int l1=LSl[b];
      for (int l2=l1;l2<=8;l2+=2){
        if (!((l2-l1)<=l && l<=(l1+l2))) continue;
        TripleMeta m{};
        m.l=l; m.l1=l1; m.l2=l2;
        m.d=2*l+1; m.d1=2*l1+1; m.d2=2*l2+1;
        m.form = (l1==0) ? ((l2==0)?2:1) : 0;   // 0=A (l1>0), 1=B (l1==0,l2>0), 2=D (0,0,0)
        m.dp4 = ((m.d+3)/4)*4;
        m.cgR = cg; cg += m.d*m.d1*m.d2;
        M.t[k] = m; k++;
      } } }
  M.nT=k; M.cgTotal=cg;
  int cgl=cg;
  for (int i=0;i<k;i++){ M.t[i].cgL=cgl; cgl += M.t[i].d*M.t[i].d1*M.t[i].d2; }
  int uv=0;
  for (int i=0;i<k;i++){
    if (M.t[i].form==0){ M.t[i].uv=uv; uv += 4*M.t[i].dp4; }
    else if (M.t[i].form==1){ M.t[i].uv=uv; uv += 2*M.t[i].dp4; }
  }
  M.uvTotal=uv;
  return M;
}

constexpr AllMeta META_H = build_meta();            // host view
static_assert(META_H.nT==42, "nT");
static_assert(META_H.cgTotal==52334, "cgTotal");
static_assert(META_H.uvTotal==2048, "uvTotal");

__device__ constexpr AllMeta META = build_meta();   // device view (identical values)

constexpr int CG_TOTAL  = 52334;
constexpr int UVS       = 2048;      // U/V slot-table stride (floats)
constexpr int ZTOT      = 4520;      // z-buffer floats in LDS (8*d^2 summed, one voxel)
constexpr int XBS       = 104;       // per-voxel xb stride in LDS
constexpr int WI_N      = 512;       // padded U work-item table: 8 wave-passes x 64 lanes

__device__ constexpr int DL[5]     = {1,5,9,13,17};
__device__ constexpr int T0G[6]    = {0,5,13,23,33,42};       // triple ranges per output-l group
__device__ constexpr int RHNB[5]   = {163840,196608,1015808,3670016,9207808}; // rh_n out offsets
__device__ constexpr int CBASE[5]  = {352,312,240,136,0};     // fpart base per li (li4 first)
__device__ constexpr int LEN5[5]   = {8,200,648,1352,2312};   // 8*d^2 per voxel
// z-buffer: per-li base, 8*d^2 each; all %4==0 for float4 copy
__device__ constexpr int ZB[5]     = {0,8,208,856,2208};
__device__ constexpr int C4[6]     = {0,2,52,214,552,1130};   // cumulative float4 counts

// phase-3 PAIRED wave schedule: li-pure passes {li, pair_base, pair_end}; lane -> pair p,
// computing columns 2p and 2p+1 (one U broadcast feeds both -> half the LDS reads, 2x ILP).
// pairs per li (per voxel) = 4d: {4,20,36,52,68}. Pair cost (padded-FMA units):
// li4=1360 li3=1216 li2=912 li1=480 li0=136. Wave totals 49664/49600/49600/49824
// (ideal 49672, imbalance 0.3% vs 8.7% of the unpaired schedule).
__device__ constexpr int SCHEDP[4][3][3] = {
  {{4,  0, 34},{1,  0,  6},{ 0, 0, 4}},
  {{4, 34, 68},{1,  6, 13},{-1, 0, 0}},
  {{3,  0, 40},{1, 13, 15},{-1, 0, 0}},
  {{3, 40, 52},{2,  0, 36},{ 1,15,20}},
};

// ---------------- kernel 1: V table — one block per (triple, abc), CG slab staged in LDS ----------------
// (R0's 1344-block form: measured rest ≈ 87-91us vs 138us for the 84-block variant — R0/R3 vs R1/R2)
// V_{t,p,q}[k2] = sum_a wA[p,a] * sum_j wB[q,j] * R_t[k2,a,j]
__global__ __launch_bounds__(128) void s2_prep(
    const float* __restrict__ w2, const float* __restrict__ w4,
    const float* __restrict__ w6, const float* __restrict__ w8,
    const float* __restrict__ cg, float* __restrict__ V)
{
  __shared__ float Rs[4928];           // max d*d1*d2 = 17*17*17 = 4913
  const int bid = blockIdx.x;
  const int t   = bid >> 5;
  const int abc = bid & 31;
  const auto &m = META.t[t];
  if (m.form == 2) return;             // (0,0,0) handled analytically in s2_main
  const int ab = abc >> 3, c = abc & 7;
  const int sz = m.d * m.d1 * m.d2;
  for (int i = threadIdx.x; i < sz; i += 128) Rs[i] = cg[m.cgR + i];   // coalesced
  __syncthreads();
  const float* ws[4] = {w2,w4,w6,w8};
  const int nout = (m.form==0 ? 4 : 2) * m.d;
  if ((int)threadIdx.x < nout){
    const int pq = threadIdx.x / m.d;
    const int k2 = threadIdx.x - pq*m.d;
    float s = 0.f;
    if (m.form==0){
      const int p = pq>>1, q = pq&1;
      const float* wA = ws[(m.l1>>1)-1] + ((ab*2+p)*8 + c)*m.d1;
      const float* wB = ws[(m.l2>>1)-1] + ((ab*2+q)*8 + c)*m.d2;
      const float* Rk = Rs + k2*m.d1*m.d2;
      for (int a=0;a<m.d1;a++){
        float t2 = 0.f;
        for (int j=0;j<m.d2;j++) t2 += wB[j]*Rk[a*m.d2+j];
        s += wA[a]*t2;
      }
    } else {
      const float* wB = ws[(m.l2>>1)-1] + ((ab*2+pq)*8 + c)*m.d2;
      const float* Rk = Rs + k2*m.d2;   // d1==1
      for (int j=0;j<m.d2;j++) s += wB[j]*Rk[j];
    }
    V[abc*UVS + m.uv + pq*m.dp4 + k2] = s;
  }
}

// ---------------- fused phase 1+2, G=2 voxels: one (t,k1) item -> 8 (or 4) U values ----------------
template<int D1>
__device__ __forceinline__ void u_itemA(const float* __restrict__ Lp, const float* xb,
    float* Ush, int dst, int dstr, int xo1, int xo2, int d2)
{
  float x0r[2*D1], x1r[2*D1];
  #pragma unroll
  for (int j=0;j<2*D1;j++){ x0r[j] = xb[xo1+j]; x1r[j] = xb[XBS+xo1+j]; }
  float a00=0.f,a01=0.f,a10=0.f,a11=0.f;
  float b00=0.f,b01=0.f,b10=0.f,b11=0.f;
  for (int b=0;b<d2;b++){
    float i00=0.f, i01=0.f, i10=0.f, i11=0.f;     // i{voxel}{p}
    const float* Lb = Lp + b*D1;                   // contiguous slab: 8 FMAs per CG load
    #pragma unroll
    for (int j=0;j<D1;j++){
      const float lv=Lb[j];
      i00+=lv*x0r[j]; i01+=lv*x0r[D1+j];
      i10+=lv*x1r[j]; i11+=lv*x1r[D1+j];
    }
    const float q00=xb[xo2+b],     q01=xb[xo2+d2+b];
    const float q10=xb[XBS+xo2+b], q11=xb[XBS+xo2+d2+b];
    a00+=q00*i00; a01+=q01*i00; a10+=q00*i01; a11+=q01*i01;
    b00+=q10*i10; b01+=q11*i10; b10+=q10*i11; b11+=q11*i11;
  }
  Ush[dst]=a00; Ush[dst+dstr]=a01; Ush[dst+2*dstr]=a10; Ush[dst+3*dstr]=a11;
  Ush[UVS+dst]=b00; Ush[UVS+dst+dstr]=b01; Ush[UVS+dst+2*dstr]=b10; Ush[UVS+dst+3*dstr]=b11;
}

__device__ __forceinline__ void u_item(const int4 w, const float* __restrict__ cg,
                                       const float* xb, float* Ush)
{
  if (w.z == 0) return;                 // idle-lane sentinel (real items have d2 field >= 5)
  const float* Lp = cg + w.x;
  const int dst = w.y & 0xFFFF, dstr = ((unsigned)w.y) >> 16;
  const int xo1 = w.z & 0xFF, xo2 = (w.z>>8)&0xFF;
  const int d1 = (w.z>>16)&0x3F, d2 = ((unsigned)w.z)>>22;
  if (d1 == 0){                         // FormB: U'[q][k1] = sum_b L[k1,b]*x2[q,b]
    float a0=0.f, a1=0.f, b0=0.f, b1=0.f;
    for (int b=0;b<d2;b++){
      const float lv=Lp[b];
      a0+=lv*xb[xo2+b];     a1+=lv*xb[xo2+d2+b];
      b0+=lv*xb[XBS+xo2+b]; b1+=lv*xb[XBS+xo2+d2+b];
    }
    Ush[dst]=a0; Ush[dst+dstr]=a1;
    Ush[UVS+dst]=b0; Ush[UVS+dst+dstr]=b1;
    return;
  }
  switch(d1){
    case 5:  u_itemA<5>(Lp,xb,Ush,dst,dstr,xo1,xo2,d2); break;
    case 9:  u_itemA<9>(Lp,xb,Ush,dst,dstr,xo1,xo2,d2); break;
    case 13: u_itemA<13>(Lp,xb,Ush,dst,dstr,xo1,xo2,d2); break;
    default: u_itemA<17>(Lp,xb,Ush,dst,dstr,xo1,xo2,d2); break;
  }
}

// ---------------- phase-3 paired column worker: one lane -> columns A and B -------------------
// z(:,k2) = sum_{t,pr} U[:,t,pr] * V[t,pr,k2] for two columns sharing every U float4 broadcast.
// V = per-lane scalar global (L2-resident, proven R2/R7); za arrays static-indexed (no scratch).
template<int LI>
__device__ __forceinline__ void col_work2(int k2A, int k2B, float rhA, float rhB, float c000,
    const float* __restrict__ VcA, const float* __restrict__ VcB, const float* Ush,
    float* zsh, int zbA, int zbB, float& sAo, float& sBo)
{
  constexpr int d   = 4*LI + 1;
  constexpr int np4 = (d+3)/4;
  float4 zaA[np4], zaB[np4];
  #pragma unroll
  for (int i=0;i<np4;i++){ zaA[i] = make_float4(0.f,0.f,0.f,0.f); zaB[i] = make_float4(0.f,0.f,0.f,0.f); }
  #pragma unroll
  for (int t=T0G[LI]; t<T0G[LI+1]; t++){
    const auto &m = META.t[t];
    if (m.form==2){
      zaA[0].x += rhA*rhA*c000;
      zaB[0].x += rhB*rhB*c000;
    } else {
      const int npr = (m.form==0)?4:2;
      #pragma unroll
      for (int pr=0;pr<npr;pr++){
        float vA = VcA[m.uv + pr*m.dp4 + k2A];
        float vB = VcB[m.uv + pr*m.dp4 + k2B];
        if (m.form==1){ vA *= rhA; vB *= rhB; }
        const float4* Up = reinterpret_cast<const float4*>(Ush + m.uv + pr*m.dp4);
        #pragma unroll
        for (int rr=0;rr<np4;rr++){
          float4 u = Up[rr];           // ONE wave-uniform LDS broadcast feeds 8 FMAs
          zaA[rr].x += u.x*vA; zaA[rr].y += u.y*vA; zaA[rr].z += u.z*vA; zaA[rr].w += u.w*vA;
          zaB[rr].x += u.x*vB; zaB[rr].y += u.y*vB; zaB[rr].z += u.z*vB; zaB[rr].w += u.w*vB;
        }
      }
    }
  }
  float sA = 0.f, sB = 0.f;
  #pragma unroll
  for (int rr=0;rr<np4;rr++){
    const float vA4[4] = {zaA[rr].x, zaA[rr].y, zaA[rr].z, zaA[rr].w};
    const float vB4[4] = {zaB[rr].x, zaB[rr].y, zaB[rr].z, zaB[rr].w};
    #pragma unroll
    for (int e=0;e<4;e++){
      const int k1 = 4*rr+e;
      if (k1 < d){
        zsh[zbA + k1*d + k2A] = vA4[e];  sA += vA4[e]*vA4[e];
        zsh[zbB + k1*d + k2B] = vB4[e];  sB += vB4[e]*vB4[e];
      }
    }
  }
  sAo = sA; sBo = sB;
}

// one li-pure paired pass for one voxel: lane -> pair p in [pbase,pend), columns 2p,2p+1
template<int LI>
__device__ __forceinline__ void do_passp(int pbase, int pend, int lane, int v,
    const float* __restrict__ Vab, const float* Ush, const float* rh0s,
    float* zsh, float* fpart, float c000)
{
  constexpr int d = 4*LI + 1;
  const int p = pbase + lane;
  if (p >= pend) return;
  const int colA = 2*p, colB = 2*p + 1;
  const int cA = colA / d, k2A = colA - cA*d;   // constexpr d -> magic mul
  const int cB = colB / d, k2B = colB - cB*d;   // pair may straddle c; handled independently
  float sA, sB;
  col_work2<LI>(k2A, k2B, rh0s[v*8+cA], rh0s[v*8+cB], c000,
                Vab + cA*UVS, Vab + cB*UVS, Ush + v*UVS,
                zsh, ZB[LI] + cA*d*d, ZB[LI] + cB*d*d, sA, sB);
  fpart[CBASE[LI] + colA] = sA;
  fpart[CBASE[LI] + colB] = sB;
}

// ---------------- kernel 2: main, one block per 2 voxels ----------------
__global__ __launch_bounds__(WGB,4) void s2_main(
    const float* __restrict__ x0, const float* __restrict__ x2, const float* __restrict__ x4,
    const float* __restrict__ x6, const float* __restrict__ x8,
    const float* __restrict__ w0, const float* __restrict__ bias,
    const float* __restrict__ cg, const int4* __restrict__ wiU,
    const float* __restrict__ V, float* __restrict__ out, float c000)
{
  __shared__ alignas(16) float SH[ZTOT + 2*UVS];   // [z (1 voxel) | U(v0) | U(v1)]
  __shared__ float xb[2*XBS];
  __shared__ float rh0s[16];
  __shared__ float fpart[360];
  float* const Ush = SH + ZTOT;
  const int tid = threadIdx.x;
  const int bid = blockIdx.x;
  const int ab  = bid >> 9;            // vox = bid*2+v; both voxels share ab

  // ---- phase 0: stage x for 2 voxels (half-block each), compute rh0 ----
  {
    const int v  = tid >> 7;           // 0 or 1
    const int t2 = tid & 127;
    const int vox = bid*2 + v;
    float* xv = xb + v*XBS;
    if (t2 < 5)        xv[t2]           = x0[vox*5  + t2];
    else if (t2 < 15)  xv[8  + (t2-5)]  = x2[vox*10 + (t2-5)];
    else if (t2 < 33)  xv[18 + (t2-15)] = x4[vox*18 + (t2-15)];
    else if (t2 < 59)  xv[36 + (t2-33)] = x6[vox*26 + (t2-33)];
    else if (t2 < 93)  xv[62 + (t2-59)] = x8[vox*34 + (t2-59)];
    else if (t2 >= 96 && t2 < 104) {
      const int c = t2 - 96;
      float s = bias[ab*8 + c];
      for (int i=0;i<5;i++) s += x0[vox*5+i] * w0[(ab*5+i)*8 + c];
      rh0s[v*8 + c] = s;
    }
  }
  __syncthreads();

  // ---- phase 1+2 fused: d1-pure LPT-balanced wave passes (2 per wave) ----
  #pragma unroll 1
  for (int it=0; it<2; it++) u_item(wiU[it*WGB + tid], cg, xb, Ush);
  __syncthreads();

  // ---- phases 3/3b/4 per voxel, z buffer reused ----
  const float* Vab = V + (ab*8)*UVS;
  const int wid = tid>>6, lane = tid&63;
  #pragma unroll 1
  for (int v=0; v<2; v++){
    const int bid2 = bid*2 + v;
    #pragma unroll 1
    for (int pi=0; pi<3; pi++){
      const int li = SCHEDP[wid][pi][0];
      if (li < 0) break;
      const int pbase = SCHEDP[wid][pi][1], pend = SCHEDP[wid][pi][2];
      switch(li){
        case 4:  do_passp<4>(pbase,pend,lane,v,Vab,Ush,rh0s,SH,fpart,c000); break;
        case 3:  do_passp<3>(pbase,pend,lane,v,Vab,Ush,rh0s,SH,fpart,c000); break;
        case 2:  do_passp<2>(pbase,pend,lane,v,Vab,Ush,rh0s,SH,fpart,c000); break;
        case 1:  do_passp<1>(pbase,pend,lane,v,Vab,Ush,rh0s,SH,fpart,c000); break;
        default: do_passp<0>(pbase,pend,lane,v,Vab,Ush,rh0s,SH,fpart,c000); break;
      }
    }
    __syncthreads();

    // phase 3b: coalesced vf4 nt copy LDS z -> global rh_n (full lines per wave instruction:
    // the ONLY safe nt-store shape — partial-line nt/direct scatter cost 5-18x HBM, R1/R3)
    for (int i4 = tid; i4 < 1130; i4 += WGB){
      int li;
      if      (i4 < C4[1]) li = 0;
      else if (i4 < C4[2]) li = 1;
      else if (i4 < C4[3]) li = 2;
      else if (i4 < C4[4]) li = 3;
      else                 li = 4;
      const int r4 = i4 - C4[li];
      const vf4 zv = *reinterpret_cast<const vf4*>(SH + ZB[li] + 4*r4);
      __builtin_nontemporal_store(zv, reinterpret_cast<vf4*>(out + RHNB[li] + bid2*LEN5[li] + 4*r4));
    }

    // phase 4: feats reduce: n_l * sum z^2, layout (A,B, 5*N*C)
    if (tid < 40){
      const int li = tid >> 3, c = tid & 7;
      const int d = DL[li];
      float s = 0.f;
      for (int k2=0;k2<d;k2++) s += fpart[CBASE[li] + c*d + k2];
      const double nl_d = 8.0*3.14159265358979323846*3.14159265358979323846/(double)(2*(2*li)+1);
      const int n = bid2 & 1023;
      __builtin_nontemporal_store((float)nl_d * s, out + ab*40960 + li*8192 + n*8 + c);
    }
    if (v==0) __syncthreads();   // protect z/fpart before next voxel overwrites
  }
}

// ---------------- host: numpy MT19937 + legacy gauss, tables + CG upload at dlopen ----------------
namespace {

struct MTRng {
  uint32_t mt[624]; int mti;
  bool has_g; double g;
  void seed(uint32_t s){
    for (int pos=0; pos<624; pos++){ mt[pos]=s; s = 1812433253u*(s^(s>>30)) + (uint32_t)pos + 1u; }
    mti = 624; has_g=false; g=0.0;
  }
  uint32_t next32(){
    if (mti >= 624){
      for (int i=0;i<624;i++){
        uint32_t y = (mt[i]&0x80000000u) | (mt[(i+1)%624]&0x7fffffffu);
        mt[i] = mt[(i+397)%624] ^ (y>>1) ^ ((y&1u) ? 0x9908b0dfu : 0u);
      }
      mti = 0;
    }
    uint32_t y = mt[mti++];
    y ^= y>>11; y ^= (y<<7)&0x9d2c5680u; y ^= (y<<15)&0xefc60000u; y ^= y>>18;
    return y;
  }
  double rk_double(){
    uint32_t a = next32()>>5, b = next32()>>6;
    return (a*67108864.0 + b)/9007199254740992.0;
  }
  double gauss(){
    if (has_g){ has_g=false; return g; }
    double f,x1,x2,r2;
    do {
      x1 = 2.0*rk_double()-1.0;
      x2 = 2.0*rk_double()-1.0;
      r2 = x1*x1 + x2*x2;
    } while (r2 >= 1.0 || r2 == 0.0);
    f = std::sqrt(-2.0*std::log(r2)/r2);
    g = f*x1; has_g = true;
    return f*x2;
  }
};

constexpr int XOFS_H[5] = {0,8,18,36,62};

struct DeviceSetup {
  float* d_cg  = nullptr;   // [CG_R | CG_L]  (2*CG_TOTAL floats)
  float* d_v   = nullptr;   // 32 * UVS floats, rewritten by s2_prep every launch
  int4*  d_wiU = nullptr;   // WI_N padded items
  float  c000  = 0.f;
  DeviceSetup(){
    // CG tables, bit-faithful numpy RandomState(42)
    std::vector<float> h(2*CG_TOTAL);
    MTRng r; r.seed(42u);
    for (int i=0;i<2*CG_TOTAL;i++) h[i] = (float)(r.gauss()*0.1);
    c000 = h[META_H.t[0].cgL] * h[META_H.t[0].cgR];

    // fused U work items, grouped by d1 (wave-pure passes), d2-desc within group
    struct HItem { int d2; int4 e; };
    std::vector<HItem> grp[5];   // 0..3: FormA d1=5/9/13/17 ; 4: FormB
    for (int t=0;t<META_H.nT;t++){
      const TripleMeta &m = META_H.t[t];
      if (m.form==0){
        const int xo1 = XOFS_H[m.l1>>1], xo2 = XOFS_H[m.l2>>1];
        for (int k1=0;k1<m.d;k1++){
          int4 e;
          e.x = m.cgL + k1*m.d1*m.d2;
          e.y = (m.uv + k1) | (m.dp4<<16);
          e.z = xo1 | (xo2<<8) | (m.d1<<16) | (m.d2<<22);
          e.w = 0;
          grp[(m.l1>>1)-1].push_back({m.d2, e});
        }
      } else if (m.form==1){
        const int xo2 = XOFS_H[m.l2>>1];
        for (int k1=0;k1<m.d;k1++){
          int4 e;
          e.x = m.cgL + k1*m.d2;
          e.y = (m.uv + k1) | (m.dp4<<16);
          e.z = (xo2<<8) | (0<<16) | (m.d2<<22);
          e.w = 0;
          grp[4].push_back({m.d2, e});
        }
      }
    }
    if (grp[0].size()!=111 || grp[1].size()!=128 || grp[2].size()!=89 ||
        grp[3].size()!=45  || grp[4].size()!=44) std::abort();
    for (int g=0; g<5; g++)
      std::stable_sort(grp[g].begin(), grp[g].end(),
                       [](const HItem&a, const HItem&b){ return a.d2 > b.d2; });

    // LPT layout onto 8 wave-passes (iter*256 + wave*64 + lane), sentinel {0,0,0,0}:
    // iter0: w0=d1x17(45)  w1=d1x13[0:64]  w2=d1x13[64:89]  w3=d1x9[0:64]
    // iter1: w0=FormB(44)  w1=d1x5[64:111] w2=d1x9[64:128]  w3=d1x5[0:64]
    // wave issue-cost: 1360 / 1384 / 1352 / 1224 (ideal 1330)
    int4 zero; zero.x=0; zero.y=0; zero.z=0; zero.w=0;
    std::vector<int4> wiU(WI_N, zero);
    auto place = [&](int iter, int w, const std::vector<HItem>& g, int s, int n){
      for (int i=0;i<n;i++) wiU[iter*256 + w*64 + i] = g[s+i].e;
    };
    place(0,0,grp[3],0,45);
    place(0,1,grp[2],0,64);
    place(0,2,grp[2],64,25);
    place(0,3,grp[1],0,64);
    place(1,0,grp[4],0,44);
    place(1,1,grp[0],64,47);
    place(1,2,grp[1],64,64);
    place(1,3,grp[0],0,64);

    (void)hipMalloc((void**)&d_cg,  sizeof(float)*2*CG_TOTAL);
    (void)hipMalloc((void**)&d_v,   sizeof(float)*32*UVS);
    (void)hipMalloc((void**)&d_wiU, sizeof(int4)*WI_N);
    (void)hipMemcpy(d_cg,  h.data(),    sizeof(float)*2*CG_TOTAL, hipMemcpyHostToDevice);
    (void)hipMemcpy(d_wiU, wiU.data(),  sizeof(int4)*WI_N,  hipMemcpyHostToDevice);
  }
};
DeviceSetup g_dev;   // static init at dlopen: pure-CPU RNG + one-time uploads (outside graph capture)

} // namespace

extern "C" void kernel_launch(void* const* d_in, const int* in_sizes, int n_in,
                              void* d_out, int out_size, void* d_ws, size_t ws_size,
                              hipStream_t stream)
{
  (void)in_sizes; (void)n_in; (void)d_ws; (void)ws_size; (void)out_size;
  const float* x0   = (const float*)d_in[0];
  const float* w0   = (const float*)d_in[1];
  const float* x2   = (const float*)d_in[2];
  const float* w2   = (const float*)d_in[3];
  const float* x4   = (const float*)d_in[4];
  const float* w4   = (const float*)d_in[5];
  const float* x6   = (const float*)d_in[6];
  const float* w6   = (const float*)d_in[7];
  const float* x8   = (const float*)d_in[8];
  const float* w8   = (const float*)d_in[9];
  const float* bias = (const float*)d_in[10];
  float* out = (float*)d_out;

  s2_prep<<<dim3(42*32), dim3(128), 0, stream>>>(w2,w4,w6,w8, g_dev.d_cg, g_dev.d_v);
  s2_main<<<dim3(2048), dim3(WGB), 0, stream>>>(x0,x2,x4,x6,x8, w0, bias,
                                                g_dev.d_cg, g_dev.d_wiU,
                                                g_dev.d_v, out, g_dev.c000);
}

// Round 10
// 250.909 us; speedup vs baseline: 1.0336x; 1.0056x over previous
//
#include <hip/hip_runtime.h>
#include <cmath>
#include <cstdint>
#include <vector>
#include <cstdlib>
#include <algorithm>

#define WGB 256

typedef float vf4 __attribute__((ext_vector_type(4)));   // native vector: OK for nontemporal builtins

// ---------------- constexpr problem metadata (evaluated identically host+device) ----------------
struct TripleMeta { int l,l1,l2,d,d1,d2,form,dp4,cgR,cgL,uv; };
struct AllMeta { TripleMeta t[48]; int nT, cgTotal, uvTotal; };

constexpr AllMeta build_meta() {
  AllMeta M{};
  const int LSl[5] = {0,2,4,6,8};
  int k=0, cg=0;
  for (int a=0;a<5;a++){ const int l=LSl[a];
    for (int b=0;b<5;b++){ const int l1=LSl[b];
      for (int l2=l1;l2<=8;l2+=2){
        if (!((l2-l1)<=l && l<=(l1+l2))) continue;
        TripleMeta m{};
        m.l=l; m.l1=l1; m.l2=l2;
        m.d=2*l+1; m.d1=2*l1+1; m.d2=2*l2+1;
        m.form = (l1==0) ? ((l2==0)?2:1) : 0;   // 0=A (l1>0), 1=B (l1==0,l2>0), 2=D (0,0,0)
        m.dp4 = ((m.d+3)/4)*4;
        m.cgR = cg; cg += m.d*m.d1*m.d2;
        M.t[k] = m; k++;
      } } }
  M.nT=k; M.cgTotal=cg;
  int cgl=cg;
  for (int i=0;i<k;i++){ M.t[i].cgL=cgl; cgl += M.t[i].d*M.t[i].d1*M.t[i].d2; }
  int uv=0;
  for (int i=0;i<k;i++){
    if (M.t[i].form==0){ M.t[i].uv=uv; uv += 4*M.t[i].dp4; }
    else if (M.t[i].form==1){ M.t[i].uv=uv; uv += 2*M.t[i].dp4; }
  }
  M.uvTotal=uv;
  return M;
}

constexpr AllMeta META_H = build_meta();            // host view
static_assert(META_H.nT==42, "nT");
static_assert(META_H.cgTotal==52334, "cgTotal");
static_assert(META_H.uvTotal==2048, "uvTotal");

__device__ constexpr AllMeta META = build_meta();   // device view (identical values)

constexpr int CG_TOTAL  = 52334;
constexpr int UVS       = 2048;      // U/V slot-table stride (floats)
constexpr int ZTOT      = 4520;      // z-buffer floats in LDS (8*d^2 summed, one voxel)
constexpr int XBS       = 104;       // per-voxel xb stride in LDS
constexpr int WI_N      = 512;       // padded U work-item table: 8 wave-passes x 64 lanes

__device__ constexpr int DL[5]     = {1,5,9,13,17};
__device__ constexpr int T0G[6]    = {0,5,13,23,33,42};       // triple ranges per output-l group
__device__ constexpr int RHNB[5]   = {163840,196608,1015808,3670016,9207808}; // rh_n out offsets
__device__ constexpr int CBASE[5]  = {352,312,240,136,0};     // fpart base per li (li4 first)
__device__ constexpr int LEN5[5]   = {8,200,648,1352,2312};   // 8*d^2 per voxel
// z-buffer: per-li base, 8*d^2 each; all %4==0 for float4 copy
__device__ constexpr int ZB[5]     = {0,8,208,856,2208};
__device__ constexpr int C4[6]     = {0,2,52,214,552,1130};   // cumulative float4 counts

// phase-3 PAIRED wave schedule: li-pure passes {li, pair_base, pair_end}; lane -> pair p,
// computing columns 2p and 2p+1 (one U broadcast feeds both -> half the LDS reads, 2x ILP).
// pairs per li (per voxel) = 4d: {4,20,36,52,68}. Pair cost (padded-FMA units):
// li4=1360 li3=1216 li2=912 li1=480 li0=136. Wave totals 49664/49600/49600/49824
// (ideal 49672, imbalance 0.3% vs 8.7% of the unpaired schedule).
__device__ constexpr int SCHEDP[4][3][3] = {
  {{4,  0, 34},{1,  0,  6},{ 0, 0, 4}},
  {{4, 34, 68},{1,  6, 13},{-1, 0, 0}},
  {{3,  0, 40},{1, 13, 15},{-1, 0, 0}},
  {{3, 40, 52},{2,  0, 36},{ 1,15,20}},
};

// ---------------- kernel 1: V table — one block per (triple, abc), CG slab staged in LDS ----------------
// (R0's 1344-block form: measured rest ≈ 87-91us vs 138us for the 84-block variant — R0/R3 vs R1/R2)
// V_{t,p,q}[k2] = sum_a wA[p,a] * sum_j wB[q,j] * R_t[k2,a,j]
__global__ __launch_bounds__(128) void s2_prep(
    const float* __restrict__ w2, const float* __restrict__ w4,
    const float* __restrict__ w6, const float* __restrict__ w8,
    const float* __restrict__ cg, float* __restrict__ V)
{
  __shared__ float Rs[4928];           // max d*d1*d2 = 17*17*17 = 4913
  const int bid = blockIdx.x;
  const int t   = bid >> 5;
  const int abc = bid & 31;
  const auto &m = META.t[t];
  if (m.form == 2) return;             // (0,0,0) handled analytically in s2_main
  const int ab = abc >> 3, c = abc & 7;
  const int sz = m.d * m.d1 * m.d2;
  for (int i = threadIdx.x; i < sz; i += 128) Rs[i] = cg[m.cgR + i];   // coalesced
  __syncthreads();
  const float* ws[4] = {w2,w4,w6,w8};
  const int nout = (m.form==0 ? 4 : 2) * m.d;
  if ((int)threadIdx.x < nout){
    const int pq = threadIdx.x / m.d;
    const int k2 = threadIdx.x - pq*m.d;
    float s = 0.f;
    if (m.form==0){
      const int p = pq>>1, q = pq&1;
      const float* wA = ws[(m.l1>>1)-1] + ((ab*2+p)*8 + c)*m.d1;
      const float* wB = ws[(m.l2>>1)-1] + ((ab*2+q)*8 + c)*m.d2;
      const float* Rk = Rs + k2*m.d1*m.d2;
      for (int a=0;a<m.d1;a++){
        float t2 = 0.f;
        for (int j=0;j<m.d2;j++) t2 += wB[j]*Rk[a*m.d2+j];
        s += wA[a]*t2;
      }
    } else {
      const float* wB = ws[(m.l2>>1)-1] + ((ab*2+pq)*8 + c)*m.d2;
      const float* Rk = Rs + k2*m.d2;   // d1==1
      for (int j=0;j<m.d2;j++) s += wB[j]*Rk[j];
    }
    V[abc*UVS + m.uv + pq*m.dp4 + k2] = s;
  }
}

// ---------------- fused phase 1+2, G=2 voxels: one (t,k1) item -> 8 (or 4) U values ----------------
template<int D1>
__device__ __forceinline__ void u_itemA(const float* __restrict__ Lp, const float* xb,
    float* Ush, int dst, int dstr, int xo1, int xo2, int d2)
{
  float x0r[2*D1], x1r[2*D1];
  #pragma unroll
  for (int j=0;j<2*D1;j++){ x0r[j] = xb[xo1+j]; x1r[j] = xb[XBS+xo1+j]; }
  float a00=0.f,a01=0.f,a10=0.f,a11=0.f;
  float b00=0.f,b01=0.f,b10=0.f,b11=0.f;
  for (int b=0;b<d2;b++){
    float i00=0.f, i01=0.f, i10=0.f, i11=0.f;     // i{voxel}{p}
    const float* Lb = Lp + b*D1;                   // contiguous slab: 8 FMAs per CG load
    #pragma unroll
    for (int j=0;j<D1;j++){
      const float lv=Lb[j];
      i00+=lv*x0r[j]; i01+=lv*x0r[D1+j];
      i10+=lv*x1r[j]; i11+=lv*x1r[D1+j];
    }
    const float q00=xb[xo2+b],     q01=xb[xo2+d2+b];
    const float q10=xb[XBS+xo2+b], q11=xb[XBS+xo2+d2+b];
    a00+=q00*i00; a01+=q01*i00; a10+=q00*i01; a11+=q01*i01;
    b00+=q10*i10; b01+=q11*i10; b10+=q10*i11; b11+=q11*i11;
  }
  Ush[dst]=a00; Ush[dst+dstr]=a01; Ush[dst+2*dstr]=a10; Ush[dst+3*dstr]=a11;
  Ush[UVS+dst]=b00; Ush[UVS+dst+dstr]=b01; Ush[UVS+dst+2*dstr]=b10; Ush[UVS+dst+3*dstr]=b11;
}

__device__ __forceinline__ void u_item(const int4 w, const float* __restrict__ cg,
                                       const float* xb, float* Ush)
{
  if (w.z == 0) return;                 // idle-lane sentinel (real items have d2 field >= 5)
  const float* Lp = cg + w.x;
  const int dst = w.y & 0xFFFF, dstr = ((unsigned)w.y) >> 16;
  const int xo1 = w.z & 0xFF, xo2 = (w.z>>8)&0xFF;
  const int d1 = (w.z>>16)&0x3F, d2 = ((unsigned)w.z)>>22;
  if (d1 == 0){                         // FormB: U'[q][k1] = sum_b L[k1,b]*x2[q,b]
    float a0=0.f, a1=0.f, b0=0.f, b1=0.f;
    for (int b=0;b<d2;b++){
      const float lv=Lp[b];
      a0+=lv*xb[xo2+b];     a1+=lv*xb[xo2+d2+b];
      b0+=lv*xb[XBS+xo2+b]; b1+=lv*xb[XBS+xo2+d2+b];
    }
    Ush[dst]=a0; Ush[dst+dstr]=a1;
    Ush[UVS+dst]=b0; Ush[UVS+dst+dstr]=b1;
    return;
  }
  switch(d1){
    case 5:  u_itemA<5>(Lp,xb,Ush,dst,dstr,xo1,xo2,d2); break;
    case 9:  u_itemA<9>(Lp,xb,Ush,dst,dstr,xo1,xo2,d2); break;
    case 13: u_itemA<13>(Lp,xb,Ush,dst,dstr,xo1,xo2,d2); break;
    default: u_itemA<17>(Lp,xb,Ush,dst,dstr,xo1,xo2,d2); break;
  }
}

// ---------------- phase-3 paired column worker: one lane -> columns A and B -------------------
// z(:,k2) = sum_{t,pr} U[:,t,pr] * V[t,pr,k2] for two columns sharing every U float4 broadcast.
// V = per-lane scalar global (L2-resident, proven R2/R7); za arrays static-indexed.
template<int LI>
__device__ __forceinline__ void col_work2(int k2A, int k2B, float rhA, float rhB, float c000,
    const float* __restrict__ VcA, const float* __restrict__ VcB, const float* Ush,
    float* zsh, int zbA, int zbB, float& sAo, float& sBo)
{
  constexpr int d   = 4*LI + 1;
  constexpr int np4 = (d+3)/4;
  float4 zaA[np4], zaB[np4];
  #pragma unroll
  for (int i=0;i<np4;i++){ zaA[i] = make_float4(0.f,0.f,0.f,0.f); zaB[i] = make_float4(0.f,0.f,0.f,0.f); }
  #pragma unroll
  for (int t=T0G[LI]; t<T0G[LI+1]; t++){
    const auto &m = META.t[t];
    if (m.form==2){
      zaA[0].x += rhA*rhA*c000;
      zaB[0].x += rhB*rhB*c000;
    } else {
      const int npr = (m.form==0)?4:2;
      #pragma unroll
      for (int pr=0;pr<npr;pr++){
        float vA = VcA[m.uv + pr*m.dp4 + k2A];
        float vB = VcB[m.uv + pr*m.dp4 + k2B];
        if (m.form==1){ vA *= rhA; vB *= rhB; }
        const float4* Up = reinterpret_cast<const float4*>(Ush + m.uv + pr*m.dp4);
        #pragma unroll
        for (int rr=0;rr<np4;rr++){
          float4 u = Up[rr];           // ONE wave-uniform LDS broadcast feeds 8 FMAs
          zaA[rr].x += u.x*vA; zaA[rr].y += u.y*vA; zaA[rr].z += u.z*vA; zaA[rr].w += u.w*vA;
          zaB[rr].x += u.x*vB; zaB[rr].y += u.y*vB; zaB[rr].z += u.z*vB; zaB[rr].w += u.w*vB;
        }
      }
    }
  }
  float sA = 0.f, sB = 0.f;
  #pragma unroll
  for (int rr=0;rr<np4;rr++){
    const float vA4[4] = {zaA[rr].x, zaA[rr].y, zaA[rr].z, zaA[rr].w};
    const float vB4[4] = {zaB[rr].x, zaB[rr].y, zaB[rr].z, zaB[rr].w};
    #pragma unroll
    for (int e=0;e<4;e++){
      const int k1 = 4*rr+e;
      if (k1 < d){
        zsh[zbA + k1*d + k2A] = vA4[e];  sA += vA4[e]*vA4[e];
        zsh[zbB + k1*d + k2B] = vB4[e];  sB += vB4[e]*vB4[e];
      }
    }
  }
  sAo = sA; sBo = sB;
}

// one li-pure paired pass for one voxel: lane -> pair p in [pbase,pend), columns 2p,2p+1
template<int LI>
__device__ __forceinline__ void do_passp(int pbase, int pend, int lane, int v,
    const float* __restrict__ Vab, const float* Ush, const float* rh0s,
    float* zsh, float* fpart, float c000)
{
  constexpr int d = 4*LI + 1;
  const int p = pbase + lane;
  if (p >= pend) return;
  const int colA = 2*p, colB = 2*p + 1;
  const int cA = colA / d, k2A = colA - cA*d;   // constexpr d -> magic mul
  const int cB = colB / d, k2B = colB - cB*d;   // pair may straddle c; handled independently
  float sA, sB;
  col_work2<LI>(k2A, k2B, rh0s[v*8+cA], rh0s[v*8+cB], c000,
                Vab + cA*UVS, Vab + cB*UVS, Ush + v*UVS,
                zsh, ZB[LI] + cA*d*d, ZB[LI] + cB*d*d, sA, sB);
  fpart[CBASE[LI] + colA] = sA;
  fpart[CBASE[LI] + colB] = sB;
}

// ---------------- kernel 2: main, one block per 2 voxels ----------------
// Occupancy is LDS-capped at 4 blocks/CU (36.9KB); amdgpu_waves_per_eu(4,4) pins the
// allocator's target there so it grants up to 128 VGPR instead of squeezing to 64 and
// spilling the paired accumulators to scratch (R8: +20MB, R9: +12MB TCC write traffic).
__global__ __attribute__((amdgpu_flat_work_group_size(256,256)))
__attribute__((amdgpu_waves_per_eu(4,4))) void s2_main(
    const float* __restrict__ x0, const float* __restrict__ x2, const float* __restrict__ x4,
    const float* __restrict__ x6, const float* __restrict__ x8,
    const float* __restrict__ w0, const float* __restrict__ bias,
    const float* __restrict__ cg, const int4* __restrict__ wiU,
    const float* __restrict__ V, float* __restrict__ out, float c000)
{
  __shared__ alignas(16) float SH[ZTOT + 2*UVS];   // [z (1 voxel) | U(v0) | U(v1)]
  __shared__ float xb[2*XBS];
  __shared__ float rh0s[16];
  __shared__ float fpart[360];
  float* const Ush = SH + ZTOT;
  const int tid = threadIdx.x;
  const int bid = blockIdx.x;
  const int ab  = bid >> 9;            // vox = bid*2+v; both voxels share ab

  // ---- phase 0: stage x for 2 voxels (half-block each), compute rh0 ----
  {
    const int v  = tid >> 7;           // 0 or 1
    const int t2 = tid & 127;
    const int vox = bid*2 + v;
    float* xv = xb + v*XBS;
    if (t2 < 5)        xv[t2]           = x0[vox*5  + t2];
    else if (t2 < 15)  xv[8  + (t2-5)]  = x2[vox*10 + (t2-5)];
    else if (t2 < 33)  xv[18 + (t2-15)] = x4[vox*18 + (t2-15)];
    else if (t2 < 59)  xv[36 + (t2-33)] = x6[vox*26 + (t2-33)];
    else if (t2 < 93)  xv[62 + (t2-59)] = x8[vox*34 + (t2-59)];
    else if (t2 >= 96 && t2 < 104) {
      const int c = t2 - 96;
      float s = bias[ab*8 + c];
      for (int i=0;i<5;i++) s += x0[vox*5+i] * w0[(ab*5+i)*8 + c];
      rh0s[v*8 + c] = s;
    }
  }
  __syncthreads();

  // ---- phase 1+2 fused: d1-pure LPT-balanced wave passes (2 per wave) ----
  #pragma unroll 1
  for (int it=0; it<2; it++) u_item(wiU[it*WGB + tid], cg, xb, Ush);
  __syncthreads();

  // ---- phases 3/3b/4 per voxel, z buffer reused ----
  const float* Vab = V + (ab*8)*UVS;
  const int wid = tid>>6, lane = tid&63;
  #pragma unroll 1
  for (int v=0; v<2; v++){
    const int bid2 = bid*2 + v;
    #pragma unroll 1
    for (int pi=0; pi<3; pi++){
      const int li = SCHEDP[wid][pi][0];
      if (li < 0) break;
      const int pbase = SCHEDP[wid][pi][1], pend = SCHEDP[wid][pi][2];
      switch(li){
        case 4:  do_passp<4>(pbase,pend,lane,v,Vab,Ush,rh0s,SH,fpart,c000); break;
        case 3:  do_passp<3>(pbase,pend,lane,v,Vab,Ush,rh0s,SH,fpart,c000); break;
        case 2:  do_passp<2>(pbase,pend,lane,v,Vab,Ush,rh0s,SH,fpart,c000); break;
        case 1:  do_passp<1>(pbase,pend,lane,v,Vab,Ush,rh0s,SH,fpart,c000); break;
        default: do_passp<0>(pbase,pend,lane,v,Vab,Ush,rh0s,SH,fpart,c000); break;
      }
    }
    __syncthreads();

    // phase 3b: coalesced vf4 nt copy LDS z -> global rh_n (full lines per wave instruction:
    // the ONLY safe nt-store shape — partial-line nt/direct scatter cost 5-18x HBM, R1/R3)
    for (int i4 = tid; i4 < 1130; i4 += WGB){
      int li;
      if      (i4 < C4[1]) li = 0;
      else if (i4 < C4[2]) li = 1;
      else if (i4 < C4[3]) li = 2;
      else if (i4 < C4[4]) li = 3;
      else                 li = 4;
      const int r4 = i4 - C4[li];
      const vf4 zv = *reinterpret_cast<const vf4*>(SH + ZB[li] + 4*r4);
      __builtin_nontemporal_store(zv, reinterpret_cast<vf4*>(out + RHNB[li] + bid2*LEN5[li] + 4*r4));
    }

    // phase 4: feats reduce: n_l * sum z^2, layout (A,B, 5*N*C)
    if (tid < 40){
      const int li = tid >> 3, c = tid & 7;
      const int d = DL[li];
      float s = 0.f;
      for (int k2=0;k2<d;k2++) s += fpart[CBASE[li] + c*d + k2];
      const double nl_d = 8.0*3.14159265358979323846*3.14159265358979323846/(double)(2*(2*li)+1);
      const int n = bid2 & 1023;
      __builtin_nontemporal_store((float)nl_d * s, out + ab*40960 + li*8192 + n*8 + c);
    }
    if (v==0) __syncthreads();   // protect z/fpart before next voxel overwrites
  }
}

// ---------------- host: numpy MT19937 + legacy gauss, tables + CG upload at dlopen ----------------
namespace {

struct MTRng {
  uint32_t mt[624]; int mti;
  bool has_g; double g;
  void seed(uint32_t s){
    for (int pos=0; pos<624; pos++){ mt[pos]=s; s = 1812433253u*(s^(s>>30)) + (uint32_t)pos + 1u; }
    mti = 624; has_g=false; g=0.0;
  }
  uint32_t next32(){
    if (mti >= 624){
      for (int i=0;i<624;i++){
        uint32_t y = (mt[i]&0x80000000u) | (mt[(i+1)%624]&0x7fffffffu);
        mt[i] = mt[(i+397)%624] ^ (y>>1) ^ ((y&1u) ? 0x9908b0dfu : 0u);
      }
      mti = 0;
    }
    uint32_t y = mt[mti++];
    y ^= y>>11; y ^= (y<<7)&0x9d2c5680u; y ^= (y<<15)&0xefc60000u; y ^= y>>18;
    return y;
  }
  double rk_double(){
    uint32_t a = next32()>>5, b = next32()>>6;
    return (a*67108864.0 + b)/9007199254740992.0;
  }
  double gauss(){
    if (has_g){ has_g=false; return g; }
    double f,x1,x2,r2;
    do {
      x1 = 2.0*rk_double()-1.0;
      x2 = 2.0*rk_double()-1.0;
      r2 = x1*x1 + x2*x2;
    } while (r2 >= 1.0 || r2 == 0.0);
    f = std::sqrt(-2.0*std::log(r2)/r2);
    g = f*x1; has_g = true;
    return f*x2;
  }
};

constexpr int XOFS_H[5] = {0,8,18,36,62};

struct DeviceSetup {
  float* d_cg  = nullptr;   // [CG_R | CG_L]  (2*CG_TOTAL floats)
  float* d_v   = nullptr;   // 32 * UVS floats, rewritten by s2_prep every launch
  int4*  d_wiU = nullptr;   // WI_N padded items
  float  c000  = 0.f;
  DeviceSetup(){
    // CG tables, bit-faithful numpy RandomState(42)
    std::vector<float> h(2*CG_TOTAL);
    MTRng r; r.seed(42u);
    for (int i=0;i<2*CG_TOTAL;i++) h[i] = (float)(r.gauss()*0.1);
    c000 = h[META_H.t[0].cgL] * h[META_H.t[0].cgR];

    // fused U work items, grouped by d1 (wave-pure passes), d2-desc within group
    struct HItem { int d2; int4 e; };
    std::vector<HItem> grp[5];   // 0..3: FormA d1=5/9/13/17 ; 4: FormB
    for (int t=0;t<META_H.nT;t++){
      const TripleMeta &m = META_H.t[t];
      if (m.form==0){
        const int xo1 = XOFS_H[m.l1>>1], xo2 = XOFS_H[m.l2>>1];
        for (int k1=0;k1<m.d;k1++){
          int4 e;
          e.x = m.cgL + k1*m.d1*m.d2;
          e.y = (m.uv + k1) | (m.dp4<<16);
          e.z = xo1 | (xo2<<8) | (m.d1<<16) | (m.d2<<22);
          e.w = 0;
          grp[(m.l1>>1)-1].push_back({m.d2, e});
        }
      } else if (m.form==1){
        const int xo2 = XOFS_H[m.l2>>1];
        for (int k1=0;k1<m.d;k1++){
          int4 e;
          e.x = m.cgL + k1*m.d2;
          e.y = (m.uv + k1) | (m.dp4<<16);
          e.z = (xo2<<8) | (0<<16) | (m.d2<<22);
          e.w = 0;
          grp[4].push_back({m.d2, e});
        }
      }
    }
    if (grp[0].size()!=111 || grp[1].size()!=128 || grp[2].size()!=89 ||
        grp[3].size()!=45  || grp[4].size()!=44) std::abort();
    for (int g=0; g<5; g++)
      std::stable_sort(grp[g].begin(), grp[g].end(),
                       [](const HItem&a, const HItem&b){ return a.d2 > b.d2; });

    // LPT layout onto 8 wave-passes (iter*256 + wave*64 + lane), sentinel {0,0,0,0}:
    // iter0: w0=d1x17(45)  w1=d1x13[0:64]  w2=d1x13[64:89]  w3=d1x9[0:64]
    // iter1: w0=FormB(44)  w1=d1x5[64:111] w2=d1x9[64:128]  w3=d1x5[0:64]
    // wave issue-cost: 1360 / 1384 / 1352 / 1224 (ideal 1330)
    int4 zero; zero.x=0; zero.y=0; zero.z=0; zero.w=0;
    std::vector<int4> wiU(WI_N, zero);
    auto place = [&](int iter, int w, const std::vector<HItem>& g, int s, int n){
      for (int i=0;i<n;i++) wiU[iter*256 + w*64 + i] = g[s+i].e;
    };
    place(0,0,grp[3],0,45);
    place(0,1,grp[2],0,64);
    place(0,2,grp[2],64,25);
    place(0,3,grp[1],0,64);
    place(1,0,grp[4],0,44);
    place(1,1,grp[0],64,47);
    place(1,2,grp[1],64,64);
    place(1,3,grp[0],0,64);

    (void)hipMalloc((void**)&d_cg,  sizeof(float)*2*CG_TOTAL);
    (void)hipMalloc((void**)&d_v,   sizeof(float)*32*UVS);
    (void)hipMalloc((void**)&d_wiU, sizeof(int4)*WI_N);
    (void)hipMemcpy(d_cg,  h.data(),    sizeof(float)*2*CG_TOTAL, hipMemcpyHostToDevice);
    (void)hipMemcpy(d_wiU, wiU.data(),  sizeof(int4)*WI_N,  hipMemcpyHostToDevice);
  }
};
DeviceSetup g_dev;   // static init at dlopen: pure-CPU RNG + one-time uploads (outside graph capture)

} // namespace

extern "C" void kernel_launch(void* const* d_in, const int* in_sizes, int n_in,
                              void* d_out, int out_size, void* d_ws, size_t ws_size,
                              hipStream_t stream)
{
  (void)in_sizes; (void)n_in; (void)d_ws; (void)ws_size; (void)out_size;
  const float* x0   = (const float*)d_in[0];
  const float* w0   = (const float*)d_in[1];
  const float* x2   = (const float*)d_in[2];
  const float* w2   = (const float*)d_in[3];
  const float* x4   = (const float*)d_in[4];
  const float* w4   = (const float*)d_in[5];
  const float* x6   = (const float*)d_in[6];
  const float* w6   = (const float*)d_in[7];
  const float* x8   = (const float*)d_in[8];
  const float* w8   = (const float*)d_in[9];
  const float* bias = (const float*)d_in[10];
  float* out = (float*)d_out;

  s2_prep<<<dim3(42*32), dim3(128), 0, stream>>>(w2,w4,w6,w8, g_dev.d_cg, g_dev.d_v);
  s2_main<<<dim3(2048), dim3(WGB), 0, stream>>>(x0,x2,x4,x6,x8, w0, bias,
                                                g_dev.d_cg, g_dev.d_wiU,
                                                g_dev.d_v, out, g_dev.c000);
}

// Round 11
// 236.631 us; speedup vs baseline: 1.0960x; 1.0603x over previous
//
#include <hip/hip_runtime.h>
#include <cmath>
#include <cstdint>
#include <vector>
#include <cstdlib>
#include <algorithm>

#define WGB 256

typedef float vf4 __attribute__((ext_vector_type(4)));   // native vector: OK for nontemporal builtins

// ---------------- constexpr problem metadata (evaluated identically host+device) ----------------
struct TripleMeta { int l,l1,l2,d,d1,d2,form,dp4,cgR,cgL,uv; };
struct AllMeta { TripleMeta t[48]; int nT, cgTotal, uvTotal; };

constexpr AllMeta build_meta() {
  AllMeta M{};
  const int LSl[5] = {0,2,4,6,8};
  int k=0, cg=0;
  for (int a=0;a<5;a++){ const int l=LSl[a];
    for (int b=0;b<5;b++){ const int l1=LSl[b];
      for (int l2=l1;l2<=8;l2+=2){
        if (!((l2-l1)<=l && l<=(l1+l2))) continue;
        TripleMeta m{};
        m.l=l; m.l1=l1; m.l2=l2;
        m.d=2*l+1; m.d1=2*l1+1; m.d2=2*l2+1;
        m.form = (l1==0) ? ((l2==0)?2:1) : 0;   // 0=A (l1>0), 1=B (l1==0,l2>0), 2=D (0,0,0)
        m.dp4 = ((m.d+3)/4)*4;
        m.cgR = cg; cg += m.d*m.d1*m.d2;
        M.t[k] = m; k++;
      } } }
  M.nT=k; M.cgTotal=cg;
  int cgl=cg;
  for (int i=0;i<k;i++){ M.t[i].cgL=cgl; cgl += M.t[i].d*M.t[i].d1*M.t[i].d2; }
  int uv=0;
  for (int i=0;i<k;i++){
    if (M.t[i].form==0){ M.t[i].uv=uv; uv += 4*M.t[i].dp4; }
    else if (M.t[i].form==1){ M.t[i].uv=uv; uv += 2*M.t[i].dp4; }
  }
  M.uvTotal=uv;
  return M;
}

constexpr AllMeta META_H = build_meta();            // host view
static_assert(META_H.nT==42, "nT");
static_assert(META_H.cgTotal==52334, "cgTotal");
static_assert(META_H.uvTotal==2048, "uvTotal");

__device__ constexpr AllMeta META = build_meta();   // device view (identical values)

constexpr int CG_TOTAL  = 52334;
constexpr int UVS       = 2048;      // U/V slot-table stride (floats)
constexpr int ZTOT      = 4520;      // z-buffer floats in LDS (8*d^2 summed, one voxel)
constexpr int XBS       = 104;       // per-voxel xb stride in LDS
constexpr int WI_N      = 512;       // padded U work-item table: 8 wave-passes x 64 lanes

__device__ constexpr int DL[5]     = {1,5,9,13,17};
__device__ constexpr int T0G[6]    = {0,5,13,23,33,42};       // triple ranges per output-l group
__device__ constexpr int RHNB[5]   = {163840,196608,1015808,3670016,9207808}; // rh_n out offsets
__device__ constexpr int CBASE[5]  = {352,312,240,136,0};     // fpart base per li (li4 first)
__device__ constexpr int LEN5[5]   = {8,200,648,1352,2312};   // 8*d^2 per voxel
// z-buffer: per-li base, 8*d^2 each; all %4==0 for float4 copy
__device__ constexpr int ZB[5]     = {0,8,208,856,2208};
__device__ constexpr int C4[6]     = {0,2,52,214,552,1130};   // cumulative float4 counts

// phase-3 static PER-VOXEL wave schedule: li-pure passes {li, col_base, col_end},
// col-space per li = 8c*d = {8,40,72,104,136}. Per-pass wave cost (scalar-FMA issue
// units): li4=680 li3=608 li2=456 li1=240 li0=68. Wave totals: 1136/1136/988/1216
// (ideal 1119). No mixed-li divergence inside a pass.
__device__ constexpr int SCHEDV[4][3][3] = {
  {{4,  0, 46},{2,  0, 36},{-1,0,0}},
  {{4, 46, 91},{2, 36, 72},{-1,0,0}},
  {{4, 91,136},{1,  0, 40},{ 0,0,8}},
  {{3,  0, 52},{3, 52,104},{-1,0,0}},
};

// ---------------- kernel 1: V table — one block per (triple, abc), CG slab staged in LDS ----------------
// (R0's 1344-block form: measured rest ≈ 87-91us vs 138us for the 84-block variant — R0/R3 vs R1/R2)
// V_{t,p,q}[k2] = sum_a wA[p,a] * sum_j wB[q,j] * R_t[k2,a,j]
__global__ __launch_bounds__(128) void s2_prep(
    const float* __restrict__ w2, const float* __restrict__ w4,
    const float* __restrict__ w6, const float* __restrict__ w8,
    const float* __restrict__ cg, float* __restrict__ V)
{
  __shared__ float Rs[4928];           // max d*d1*d2 = 17*17*17 = 4913
  const int bid = blockIdx.x;
  const int t   = bid >> 5;
  const int abc = bid & 31;
  const auto &m = META.t[t];
  if (m.form == 2) return;             // (0,0,0) handled analytically in s2_main
  const int ab = abc >> 3, c = abc & 7;
  const int sz = m.d * m.d1 * m.d2;
  for (int i = threadIdx.x; i < sz; i += 128) Rs[i] = cg[m.cgR + i];   // coalesced
  __syncthreads();
  const float* ws[4] = {w2,w4,w6,w8};
  const int nout = (m.form==0 ? 4 : 2) * m.d;
  if ((int)threadIdx.x < nout){
    const int pq = threadIdx.x / m.d;
    const int k2 = threadIdx.x - pq*m.d;
    float s = 0.f;
    if (m.form==0){
      const int p = pq>>1, q = pq&1;
      const float* wA = ws[(m.l1>>1)-1] + ((ab*2+p)*8 + c)*m.d1;
      const float* wB = ws[(m.l2>>1)-1] + ((ab*2+q)*8 + c)*m.d2;
      const float* Rk = Rs + k2*m.d1*m.d2;
      for (int a=0;a<m.d1;a++){
        float t2 = 0.f;
        for (int j=0;j<m.d2;j++) t2 += wB[j]*Rk[a*m.d2+j];
        s += wA[a]*t2;
      }
    } else {
      const float* wB = ws[(m.l2>>1)-1] + ((ab*2+pq)*8 + c)*m.d2;
      const float* Rk = Rs + k2*m.d2;   // d1==1
      for (int j=0;j<m.d2;j++) s += wB[j]*Rk[j];
    }
    V[abc*UVS + m.uv + pq*m.dp4 + k2] = s;
  }
}

// ---------------- fused phase 1+2, G=2 voxels: one (t,k1) item -> 8 (or 4) U values ----------------
template<int D1>
__device__ __forceinline__ void u_itemA(const float* __restrict__ Lp, const float* xb,
    float* Ush, int dst, int dstr, int xo1, int xo2, int d2)
{
  float x0r[2*D1], x1r[2*D1];
  #pragma unroll
  for (int j=0;j<2*D1;j++){ x0r[j] = xb[xo1+j]; x1r[j] = xb[XBS+xo1+j]; }
  float a00=0.f,a01=0.f,a10=0.f,a11=0.f;
  float b00=0.f,b01=0.f,b10=0.f,b11=0.f;
  for (int b=0;b<d2;b++){
    float i00=0.f, i01=0.f, i10=0.f, i11=0.f;     // i{voxel}{p}
    const float* Lb = Lp + b*D1;                   // contiguous slab: 8 FMAs per CG load
    #pragma unroll
    for (int j=0;j<D1;j++){
      const float lv=Lb[j];
      i00+=lv*x0r[j]; i01+=lv*x0r[D1+j];
      i10+=lv*x1r[j]; i11+=lv*x1r[D1+j];
    }
    const float q00=xb[xo2+b],     q01=xb[xo2+d2+b];
    const float q10=xb[XBS+xo2+b], q11=xb[XBS+xo2+d2+b];
    a00+=q00*i00; a01+=q01*i00; a10+=q00*i01; a11+=q01*i01;
    b00+=q10*i10; b01+=q11*i10; b10+=q10*i11; b11+=q11*i11;
  }
  Ush[dst]=a00; Ush[dst+dstr]=a01; Ush[dst+2*dstr]=a10; Ush[dst+3*dstr]=a11;
  Ush[UVS+dst]=b00; Ush[UVS+dst+dstr]=b01; Ush[UVS+dst+2*dstr]=b10; Ush[UVS+dst+3*dstr]=b11;
}

__device__ __forceinline__ void u_item(const int4 w, const float* __restrict__ cg,
                                       const float* xb, float* Ush)
{
  if (w.z == 0) return;                 // idle-lane sentinel (real items have d2 field >= 5)
  const float* Lp = cg + w.x;
  const int dst = w.y & 0xFFFF, dstr = ((unsigned)w.y) >> 16;
  const int xo1 = w.z & 0xFF, xo2 = (w.z>>8)&0xFF;
  const int d1 = (w.z>>16)&0x3F, d2 = ((unsigned)w.z)>>22;
  if (d1 == 0){                         // FormB: U'[q][k1] = sum_b L[k1,b]*x2[q,b]
    float a0=0.f, a1=0.f, b0=0.f, b1=0.f;
    for (int b=0;b<d2;b++){
      const float lv=Lp[b];
      a0+=lv*xb[xo2+b];     a1+=lv*xb[xo2+d2+b];
      b0+=lv*xb[XBS+xo2+b]; b1+=lv*xb[XBS+xo2+d2+b];
    }
    Ush[dst]=a0; Ush[dst+dstr]=a1;
    Ush[UVS+dst]=b0; Ush[UVS+dst+dstr]=b1;
    return;
  }
  switch(d1){
    case 5:  u_itemA<5>(Lp,xb,Ush,dst,dstr,xo1,xo2,d2); break;
    case 9:  u_itemA<9>(Lp,xb,Ush,dst,dstr,xo1,xo2,d2); break;
    case 13: u_itemA<13>(Lp,xb,Ush,dst,dstr,xo1,xo2,d2); break;
    default: u_itemA<17>(Lp,xb,Ush,dst,dstr,xo1,xo2,d2); break;
  }
}

// ---------------- phase-3 column worker (one (c, l, k2) column) -> z into LDS ----------------
// (R2/R7's proven form, measured 148us twice: V = per-lane scalar global (L2), U = wave-uniform
//  float4 LDS broadcast over dp4-padded [pr][k1] slabs, z scattered to LDS.)
template<int LI>
__device__ __forceinline__ float col_work(int k2, float rh0c, float c000,
    const float* __restrict__ Vc, const float* Ush,
    float* zsh, int zb)
{
  constexpr int d   = 4*LI + 1;
  constexpr int np4 = (d+3)/4;
  float4 za[np4];
  #pragma unroll
  for (int i=0;i<np4;i++) za[i] = make_float4(0.f,0.f,0.f,0.f);
  #pragma unroll
  for (int t=T0G[LI]; t<T0G[LI+1]; t++){
    const auto &m = META.t[t];
    if (m.form==2){
      za[0].x += rh0c*rh0c*c000;
    } else {
      const int npr = (m.form==0)?4:2;
      #pragma unroll
      for (int pr=0;pr<npr;pr++){
        float v = Vc[m.uv + pr*m.dp4 + k2];
        if (m.form==1) v *= rh0c;
        const float4* Up = reinterpret_cast<const float4*>(Ush + m.uv + pr*m.dp4);
        #pragma unroll
        for (int rr=0;rr<np4;rr++){
          float4 u = Up[rr];           // wave-uniform LDS broadcast
          za[rr].x += u.x*v; za[rr].y += u.y*v; za[rr].z += u.z*v; za[rr].w += u.w*v;
        }
      }
    }
  }
  float s = 0.f;
  #pragma unroll
  for (int rr=0;rr<np4;rr++){
    const float vals[4] = {za[rr].x, za[rr].y, za[rr].z, za[rr].w};
    #pragma unroll
    for (int e=0;e<4;e++){
      const int k1 = 4*rr+e;
      if (k1 < d){
        zsh[zb + k1*d + k2] = vals[e];   // LDS scatter (d odd -> conflict-light); global is ph3b
        s += vals[e]*vals[e];
      }
    }
  }
  return s;
}

// one li-pure pass for one voxel: lane -> (c,k2) column within [base,end)
template<int LI>
__device__ __forceinline__ void do_passv(int base, int end, int lane, int v,
    const float* __restrict__ Vab, const float* Ush, const float* rh0s,
    float* zsh, float* fpart, float c000)
{
  constexpr int d = 4*LI + 1;
  const int col = base + lane;
  if (col >= end) return;
  const int c  = col / d;               // constexpr d -> magic mul
  const int k2 = col - c*d;
  const float s = col_work<LI>(k2, rh0s[v*8+c], c000, Vab + c*UVS, Ush + v*UVS,
                               zsh, ZB[LI] + c*d*d);
  fpart[CBASE[LI] + col] = s;
}

// ---------------- kernel 2: main, one block per 2 voxels ----------------
__global__ __launch_bounds__(WGB,4) void s2_main(
    const float* __restrict__ x0, const float* __restrict__ x2, const float* __restrict__ x4,
    const float* __restrict__ x6, const float* __restrict__ x8,
    const float* __restrict__ w0, const float* __restrict__ bias,
    const float* __restrict__ cg, const int4* __restrict__ wiU,
    const float* __restrict__ V, float* __restrict__ out, float c000)
{
  __shared__ alignas(16) float SH[ZTOT + 2*UVS];   // [z (1 voxel) | U(v0) | U(v1)]
  __shared__ float xb[2*XBS];
  __shared__ float rh0s[16];
  __shared__ float fpart[360];
  float* const Ush = SH + ZTOT;
  const int tid = threadIdx.x;
  const int bid = blockIdx.x;
  const int ab  = bid >> 9;            // vox = bid*2+v; both voxels share ab

  // ---- phase 0: stage x for 2 voxels (half-block each), compute rh0 ----
  {
    const int v  = tid >> 7;           // 0 or 1
    const int t2 = tid & 127;
    const int vox = bid*2 + v;
    float* xv = xb + v*XBS;
    if (t2 < 5)        xv[t2]           = x0[vox*5  + t2];
    else if (t2 < 15)  xv[8  + (t2-5)]  = x2[vox*10 + (t2-5)];
    else if (t2 < 33)  xv[18 + (t2-15)] = x4[vox*18 + (t2-15)];
    else if (t2 < 59)  xv[36 + (t2-33)] = x6[vox*26 + (t2-33)];
    else if (t2 < 93)  xv[62 + (t2-59)] = x8[vox*34 + (t2-59)];
    else if (t2 >= 96 && t2 < 104) {
      const int c = t2 - 96;
      float s = bias[ab*8 + c];
      for (int i=0;i<5;i++) s += x0[vox*5+i] * w0[(ab*5+i)*8 + c];
      rh0s[v*8 + c] = s;
    }
  }
  __syncthreads();

  // ---- phase 1+2 fused: d1-pure LPT-balanced wave passes (2 per wave) ----
  #pragma unroll 1
  for (int it=0; it<2; it++) u_item(wiU[it*WGB + tid], cg, xb, Ush);
  __syncthreads();

  // ---- phases 3/3b/4 per voxel, z buffer reused ----
  const float* Vab = V + (ab*8)*UVS;
  const int wid = tid>>6, lane = tid&63;
  #pragma unroll 1
  for (int v=0; v<2; v++){
    const int bid2 = bid*2 + v;
    #pragma unroll 1
    for (int pi=0; pi<3; pi++){
      const int li = SCHEDV[wid][pi][0];
      if (li < 0) break;
      const int base = SCHEDV[wid][pi][1], end = SCHEDV[wid][pi][2];
      switch(li){
        case 4:  do_passv<4>(base,end,lane,v,Vab,Ush,rh0s,SH,fpart,c000); break;
        case 3:  do_passv<3>(base,end,lane,v,Vab,Ush,rh0s,SH,fpart,c000); break;
        case 2:  do_passv<2>(base,end,lane,v,Vab,Ush,rh0s,SH,fpart,c000); break;
        case 1:  do_passv<1>(base,end,lane,v,Vab,Ush,rh0s,SH,fpart,c000); break;
        default: do_passv<0>(base,end,lane,v,Vab,Ush,rh0s,SH,fpart,c000); break;
      }
    }
    __syncthreads();

    // phase 3b: coalesced vf4 nt copy LDS z -> global rh_n (full lines per wave instruction:
    // the ONLY safe nt-store shape — partial-line nt/direct scatter cost 5-18x HBM, R1/R3)
    for (int i4 = tid; i4 < 1130; i4 += WGB){
      int li;
      if      (i4 < C4[1]) li = 0;
      else if (i4 < C4[2]) li = 1;
      else if (i4 < C4[3]) li = 2;
      else if (i4 < C4[4]) li = 3;
      else                 li = 4;
      const int r4 = i4 - C4[li];
      const vf4 zv = *reinterpret_cast<const vf4*>(SH + ZB[li] + 4*r4);
      __builtin_nontemporal_store(zv, reinterpret_cast<vf4*>(out + RHNB[li] + bid2*LEN5[li] + 4*r4));
    }

    // phase 4: feats reduce: n_l * sum z^2, layout (A,B, 5*N*C)
    if (tid < 40){
      const int li = tid >> 3, c = tid & 7;
      const int d = DL[li];
      float s = 0.f;
      for (int k2=0;k2<d;k2++) s += fpart[CBASE[li] + c*d + k2];
      const double nl_d = 8.0*3.14159265358979323846*3.14159265358979323846/(double)(2*(2*li)+1);
      const int n = bid2 & 1023;
      __builtin_nontemporal_store((float)nl_d * s, out + ab*40960 + li*8192 + n*8 + c);
    }
    if (v==0) __syncthreads();   // protect z/fpart before next voxel overwrites
  }
}

// ---------------- host: numpy MT19937 + legacy gauss, tables + CG upload at dlopen ----------------
namespace {

struct MTRng {
  uint32_t mt[624]; int mti;
  bool has_g; double g;
  void seed(uint32_t s){
    for (int pos=0; pos<624; pos++){ mt[pos]=s; s = 1812433253u*(s^(s>>30)) + (uint32_t)pos + 1u; }
    mti = 624; has_g=false; g=0.0;
  }
  uint32_t next32(){
    if (mti >= 624){
      for (int i=0;i<624;i++){
        uint32_t y = (mt[i]&0x80000000u) | (mt[(i+1)%624]&0x7fffffffu);
        mt[i] = mt[(i+397)%624] ^ (y>>1) ^ ((y&1u) ? 0x9908b0dfu : 0u);
      }
      mti = 0;
    }
    uint32_t y = mt[mti++];
    y ^= y>>11; y ^= (y<<7)&0x9d2c5680u; y ^= (y<<15)&0xefc60000u; y ^= y>>18;
    return y;
  }
  double rk_double(){
    uint32_t a = next32()>>5, b = next32()>>6;
    return (a*67108864.0 + b)/9007199254740992.0;
  }
  double gauss(){
    if (has_g){ has_g=false; return g; }
    double f,x1,x2,r2;
    do {
      x1 = 2.0*rk_double()-1.0;
      x2 = 2.0*rk_double()-1.0;
      r2 = x1*x1 + x2*x2;
    } while (r2 >= 1.0 || r2 == 0.0);
    f = std::sqrt(-2.0*std::log(r2)/r2);
    g = f*x1; has_g = true;
    return f*x2;
  }
};

constexpr int XOFS_H[5] = {0,8,18,36,62};

struct DeviceSetup {
  float* d_cg  = nullptr;   // [CG_R | CG_L]  (2*CG_TOTAL floats)
  float* d_v   = nullptr;   // 32 * UVS floats, rewritten by s2_prep every launch
  int4*  d_wiU = nullptr;   // WI_N padded items
  float  c000  = 0.f;
  DeviceSetup(){
    // CG tables, bit-faithful numpy RandomState(42)
    std::vector<float> h(2*CG_TOTAL);
    MTRng r; r.seed(42u);
    for (int i=0;i<2*CG_TOTAL;i++) h[i] = (float)(r.gauss()*0.1);
    c000 = h[META_H.t[0].cgL] * h[META_H.t[0].cgR];

    // fused U work items, grouped by d1 (wave-pure passes), d2-desc within group
    struct HItem { int d2; int4 e; };
    std::vector<HItem> grp[5];   // 0..3: FormA d1=5/9/13/17 ; 4: FormB
    for (int t=0;t<META_H.nT;t++){
      const TripleMeta &m = META_H.t[t];
      if (m.form==0){
        const int xo1 = XOFS_H[m.l1>>1], xo2 = XOFS_H[m.l2>>1];
        for (int k1=0;k1<m.d;k1++){
          int4 e;
          e.x = m.cgL + k1*m.d1*m.d2;
          e.y = (m.uv + k1) | (m.dp4<<16);
          e.z = xo1 | (xo2<<8) | (m.d1<<16) | (m.d2<<22);
          e.w = 0;
          grp[(m.l1>>1)-1].push_back({m.d2, e});
        }
      } else if (m.form==1){
        const int xo2 = XOFS_H[m.l2>>1];
        for (int k1=0;k1<m.d;k1++){
          int4 e;
          e.x = m.cgL + k1*m.d2;
          e.y = (m.uv + k1) | (m.dp4<<16);
          e.z = (xo2<<8) | (0<<16) | (m.d2<<22);
          e.w = 0;
          grp[4].push_back({m.d2, e});
        }
      }
    }
    if (grp[0].size()!=111 || grp[1].size()!=128 || grp[2].size()!=89 ||
        grp[3].size()!=45  || grp[4].size()!=44) std::abort();
    for (int g=0; g<5; g++)
      std::stable_sort(grp[g].begin(), grp[g].end(),
                       [](const HItem&a, const HItem&b){ return a.d2 > b.d2; });

    // LPT layout onto 8 wave-passes (iter*256 + wave*64 + lane), sentinel {0,0,0,0}:
    // iter0: w0=d1x17(45)  w1=d1x13[0:64]  w2=d1x13[64:89]  w3=d1x9[0:64]
    // iter1: w0=FormB(44)  w1=d1x5[64:111] w2=d1x9[64:128]  w3=d1x5[0:64]
    // wave issue-cost: 1360 / 1384 / 1352 / 1224 (ideal 1330)
    int4 zero; zero.x=0; zero.y=0; zero.z=0; zero.w=0;
    std::vector<int4> wiU(WI_N, zero);
    auto place = [&](int iter, int w, const std::vector<HItem>& g, int s, int n){
      for (int i=0;i<n;i++) wiU[iter*256 + w*64 + i] = g[s+i].e;
    };
    place(0,0,grp[3],0,45);
    place(0,1,grp[2],0,64);
    place(0,2,grp[2],64,25);
    place(0,3,grp[1],0,64);
    place(1,0,grp[4],0,44);
    place(1,1,grp[0],64,47);
    place(1,2,grp[1],64,64);
    place(1,3,grp[0],0,64);

    (void)hipMalloc((void**)&d_cg,  sizeof(float)*2*CG_TOTAL);
    (void)hipMalloc((void**)&d_v,   sizeof(float)*32*UVS);
    (void)hipMalloc((void**)&d_wiU, sizeof(int4)*WI_N);
    (void)hipMemcpy(d_cg,  h.data(),    sizeof(float)*2*CG_TOTAL, hipMemcpyHostToDevice);
    (void)hipMemcpy(d_wiU, wiU.data(),  sizeof(int4)*WI_N,  hipMemcpyHostToDevice);
  }
};
DeviceSetup g_dev;   // static init at dlopen: pure-CPU RNG + one-time uploads (outside graph capture)

} // namespace

extern "C" void kernel_launch(void* const* d_in, const int* in_sizes, int n_in,
                              void* d_out, int out_size, void* d_ws, size_t ws_size,
                              hipStream_t stream)
{
  (void)in_sizes; (void)n_in; (void)d_ws; (void)ws_size; (void)out_size;
  const float* x0   = (const float*)d_in[0];
  const float* w0   = (const float*)d_in[1];
  const float* x2   = (const float*)d_in[2];
  const float* w2   = (const float*)d_in[3];
  const float* x4   = (const float*)d_in[4];
  const float* w4   = (const float*)d_in[5];
  const float* x6   = (const float*)d_in[6];
  const float* w6   = (const float*)d_in[7];
  const float* x8   = (const float*)d_in[8];
  const float* w8   = (const float*)d_in[9];
  const float* bias = (const float*)d_in[10];
  float* out = (float*)d_out;

  s2_prep<<<dim3(42*32), dim3(128), 0, stream>>>(w2,w4,w6,w8, g_dev.d_cg, g_dev.d_v);
  s2_main<<<dim3(2048), dim3(WGB), 0, stream>>>(x0,x2,x4,x6,x8, w0, bias,
                                                g_dev.d_cg, g_dev.d_wiU,
                                                g_dev.d_v, out, g_dev.c000);
}

// Round 13
// 227.812 us; speedup vs baseline: 1.1384x; 1.0387x over previous
//
#include <hip/hip_runtime.h>
#include <cmath>
#include <cstdint>
#include <vector>
#include <cstdlib>
#include <algorithm>

#define WGB 256

typedef float vf4 __attribute__((ext_vector_type(4)));   // native vector: OK for nontemporal builtins

// ---------------- constexpr problem metadata (evaluated identically host+device) ----------------
struct TripleMeta { int l,l1,l2,d,d1,d2,form,dp4,cgR,cgL,uvV,uvU; };
struct AllMeta { TripleMeta t[48]; int nT, cgTotal, uvTotal, uvUTotal; };

constexpr AllMeta build_meta() {
  AllMeta M{};
  const int LSl[5] = {0,2,4,6,8};
  int k=0, cg=0;
  for (int a=0;a<5;a++){ const int l=LSl[a];
    for (int b=0;b<5;b++){ const int l1=LSl[b];
      for (int l2=l1;l2<=8;l2+=2){
        if (!((l2-l1)<=l && l<=(l1+l2))) continue;
        TripleMeta m{};
        m.l=l; m.l1=l1; m.l2=l2;
        m.d=2*l+1; m.d1=2*l1+1; m.d2=2*l2+1;
        m.form = (l1==0) ? ((l2==0)?2:1) : 0;   // 0=A (l1>0), 1=B (l1==0,l2>0), 2=D (0,0,0)
        m.dp4 = ((m.d+3)/4)*4;
        m.cgR = cg; cg += m.d*m.d1*m.d2;
        M.t[k] = m; k++;
      } } }
  M.nT=k; M.cgTotal=cg;
  int cgl=cg;
  for (int i=0;i<k;i++){ M.t[i].cgL=cgl; cgl += M.t[i].d*M.t[i].d1*M.t[i].d2; }
  int uv=0, uvu=0;
  for (int i=0;i<k;i++){
    // V table (GLOBAL, prep output): pq-major, dp4-padded — unchanged (k2-scalar reads).
    // U table (LDS): k1-major, pr-minor, PAD-FREE (R6-proven math). A: [d][4]; B: [d][2]+2 pad
    // -> every uvU stays %4==0 (A adds 4d; B adds 2d+2, d odd -> both %4==0): float4-aligned.
    if (M.t[i].form==0){ M.t[i].uvV=uv; uv += 4*M.t[i].dp4; M.t[i].uvU=uvu; uvu += 4*M.t[i].d; }
    else if (M.t[i].form==1){ M.t[i].uvV=uv; uv += 2*M.t[i].dp4; M.t[i].uvU=uvu; uvu += 2*M.t[i].d + 2; }
  }
  M.uvTotal=uv; M.uvUTotal=uvu;
  return M;
}

constexpr AllMeta META_H = build_meta();            // host view
static_assert(META_H.nT==42, "nT");
static_assert(META_H.cgTotal==52334, "cgTotal");
static_assert(META_H.uvTotal==2048, "uvTotal");
static_assert(META_H.uvUTotal==1588, "uvUTotal");

__device__ constexpr AllMeta META = build_meta();   // device view (identical values)

constexpr int CG_TOTAL  = 52334;
constexpr int UVS       = 2048;      // V slot-table stride in GLOBAL (floats, dp4-padded)
constexpr int UVSU      = 1588;      // packed U stride in LDS (k1-major; %4==0, 16B-aligned base)
constexpr int ZTOT      = 4520;      // z-buffer floats in LDS (8*d^2 summed, one voxel)
constexpr int XBS       = 104;       // per-voxel xb stride in LDS
constexpr int WI_N      = 512;       // padded U work-item table: 8 wave-passes x 64 lanes

// LDS layout (floats): z [0,4520) — xb[208] aliases its head (xb dead before first z write, R4-proven)
//                      U [4520, 4520+2*1588) | rh0s [7696,7712) | fpart [7712,8072)
constexpr int UOFF  = 4520;
constexpr int ROFF  = UOFF + 2*UVSU;          // 7696
constexpr int FOFF  = ROFF + 16;              // 7712
constexpr int SHTOT = FOFF + 360;             // 8072 floats = 32288 B -> 5 blocks/CU (20 waves)

__device__ constexpr int DL[5]     = {1,5,9,13,17};
__device__ constexpr int T0G[6]    = {0,5,13,23,33,42};       // triple ranges per output-l group
__device__ constexpr int RHNB[5]   = {163840,196608,1015808,3670016,9207808}; // rh_n out offsets
__device__ constexpr int CBASE[5]  = {352,312,240,136,0};     // fpart base per li (li4 first)
__device__ constexpr int LEN5[5]   = {8,200,648,1352,2312};   // 8*d^2 per voxel
// z-buffer: per-li base, 8*d^2 each; all %4==0 for float4 copy
__device__ constexpr int ZB[5]     = {0,8,208,856,2208};
__device__ constexpr int C4[6]     = {0,2,52,214,552,1130};   // cumulative float4 counts

// phase-3 static PER-VOXEL wave schedule: li-pure passes {li, col_base, col_end},
// col-space per li = 8c*d = {8,40,72,104,136}. Wave totals 1136/1136/988/1216 (ideal 1119).
__device__ constexpr int SCHEDV[4][3][3] = {
  {{4,  0, 46},{2,  0, 36},{-1,0,0}},
  {{4, 46, 91},{2, 36, 72},{-1,0,0}},
  {{4, 91,136},{1,  0, 40},{ 0,0,8}},
  {{3,  0, 52},{3, 52,104},{-1,0,0}},
};

// ---------------- kernel 1: V table — one block per (triple, abc), CG slab staged in LDS ----------------
// (R0's 1344-block form: measured rest ≈ 72-91us vs 138us for the 84-block variant)
// V_{t,p,q}[k2] = sum_a wA[p,a] * sum_j wB[q,j] * R_t[k2,a,j]
__global__ __launch_bounds__(128) void s2_prep(
    const float* __restrict__ w2, const float* __restrict__ w4,
    const float* __restrict__ w6, const float* __restrict__ w8,
    const float* __restrict__ cg, float* __restrict__ V)
{
  __shared__ float Rs[4928];           // max d*d1*d2 = 17*17*17 = 4913
  const int bid = blockIdx.x;
  const int t   = bid >> 5;
  const int abc = bid & 31;
  const auto &m = META.t[t];
  if (m.form == 2) return;             // (0,0,0) handled analytically in s2_main
  const int ab = abc >> 3, c = abc & 7;
  const int sz = m.d * m.d1 * m.d2;
  for (int i = threadIdx.x; i < sz; i += 128) Rs[i] = cg[m.cgR + i];   // coalesced
  __syncthreads();
  const float* ws[4] = {w2,w4,w6,w8};
  const int nout = (m.form==0 ? 4 : 2) * m.d;
  if ((int)threadIdx.x < nout){
    const int pq = threadIdx.x / m.d;
    const int k2 = threadIdx.x - pq*m.d;
    float s = 0.f;
    if (m.form==0){
      const int p = pq>>1, q = pq&1;
      const float* wA = ws[(m.l1>>1)-1] + ((ab*2+p)*8 + c)*m.d1;
      const float* wB = ws[(m.l2>>1)-1] + ((ab*2+q)*8 + c)*m.d2;
      const float* Rk = Rs + k2*m.d1*m.d2;
      for (int a=0;a<m.d1;a++){
        float t2 = 0.f;
        for (int j=0;j<m.d2;j++) t2 += wB[j]*Rk[a*m.d2+j];
        s += wA[a]*t2;
      }
    } else {
      const float* wB = ws[(m.l2>>1)-1] + ((ab*2+pq)*8 + c)*m.d2;
      const float* Rk = Rs + k2*m.d2;   // d1==1
      for (int j=0;j<m.d2;j++) s += wB[j]*Rk[j];
    }
    V[abc*UVS + m.uvV + pq*m.dp4 + k2] = s;
  }
}

// ---------------- fused phase 1+2, G=2 voxels: one (t,k1) item -> 8 (or 4) U values ----------------
// U destination is k1-major/pr-minor: dst = uvU + k1*npr, dstr = 1 (pr stride). (R6-proven)
template<int D1>
__device__ __forceinline__ void u_itemA(const float* __restrict__ Lp, const float* xb,
    float* Ush, int dst, int dstr, int xo1, int xo2, int d2)
{
  float x0r[2*D1], x1r[2*D1];
  #pragma unroll
  for (int j=0;j<2*D1;j++){ x0r[j] = xb[xo1+j]; x1r[j] = xb[XBS+xo1+j]; }
  float a00=0.f,a01=0.f,a10=0.f,a11=0.f;
  float b00=0.f,b01=0.f,b10=0.f,b11=0.f;
  for (int b=0;b<d2;b++){
    float i00=0.f, i01=0.f, i10=0.f, i11=0.f;     // i{voxel}{p}
    const float* Lb = Lp + b*D1;                   // contiguous slab: 8 FMAs per CG load
    #pragma unroll
    for (int j=0;j<D1;j++){
      const float lv=Lb[j];
      i00+=lv*x0r[j]; i01+=lv*x0r[D1+j];
      i10+=lv*x1r[j]; i11+=lv*x1r[D1+j];
    }
    const float q00=xb[xo2+b],     q01=xb[xo2+d2+b];
    const float q10=xb[XBS+xo2+b], q11=xb[XBS+xo2+d2+b];
    a00+=q00*i00; a01+=q01*i00; a10+=q00*i01; a11+=q01*i01;
    b00+=q10*i10; b01+=q11*i10; b10+=q10*i11; b11+=q11*i11;
  }
  Ush[dst]=a00; Ush[dst+dstr]=a01; Ush[dst+2*dstr]=a10; Ush[dst+3*dstr]=a11;
  Ush[UVSU+dst]=b00; Ush[UVSU+dst+dstr]=b01; Ush[UVSU+dst+2*dstr]=b10; Ush[UVSU+dst+3*dstr]=b11;
}

__device__ __forceinline__ void u_item(const int4 w, const float* __restrict__ cg,
                                       const float* xb, float* Ush)
{
  if (w.z == 0) return;                 // idle-lane sentinel (real items have d2 field >= 5)
  const float* Lp = cg + w.x;
  const int dst = w.y & 0xFFFF, dstr = ((unsigned)w.y) >> 16;
  const int xo1 = w.z & 0xFF, xo2 = (w.z>>8)&0xFF;
  const int d1 = (w.z>>16)&0x3F, d2 = ((unsigned)w.z)>>22;
  if (d1 == 0){                         // FormB: U'[q][k1] = sum_b L[k1,b]*x2[q,b]
    float a0=0.f, a1=0.f, b0=0.f, b1=0.f;
    for (int b=0;b<d2;b++){
      const float lv=Lp[b];
      a0+=lv*xb[xo2+b];     a1+=lv*xb[xo2+d2+b];
      b0+=lv*xb[XBS+xo2+b]; b1+=lv*xb[XBS+xo2+d2+b];
    }
    Ush[dst]=a0; Ush[dst+dstr]=a1;
    Ush[UVSU+dst]=b0; Ush[UVSU+dst+dstr]=b1;
    return;
  }
  switch(d1){
    case 5:  u_itemA<5>(Lp,xb,Ush,dst,dstr,xo1,xo2,d2); break;
    case 9:  u_itemA<9>(Lp,xb,Ush,dst,dstr,xo1,xo2,d2); break;
    case 13: u_itemA<13>(Lp,xb,Ush,dst,dstr,xo1,xo2,d2); break;
    default: u_itemA<17>(Lp,xb,Ush,dst,dstr,xo1,xo2,d2); break;
  }
}

// ---------------- phase-3 column worker: lane owns (c,k2); k1 is the register axis -----------
// z(k1,k2) = sum_{t,pr} U[k1,pr] * V[pr,k2]. V = per-lane scalar global (L2, R2/R7-proven);
// U = wave-uniform float4/float2 LDS broadcast over the PAD-FREE k1-major layout (R6-proven
// math, ~15% fewer FMAs than the dp4-padded sweep). z scattered to LDS; vf4 copy is ph3b.
template<int LI>
__device__ __forceinline__ float col_work(int k2, float rh0c, float c000,
    const float* __restrict__ Vc, const float* Ush_v,
    float* zsh, int zb)
{
  constexpr int d = 4*LI + 1;
  float za[d];
  #pragma unroll
  for (int i=0;i<d;i++) za[i] = 0.f;
  #pragma unroll
  for (int t=T0G[LI]; t<T0G[LI+1]; t++){
    const auto &m = META.t[t];
    if (m.form==2){
      za[0] += rh0c*rh0c*c000;
    } else if (m.form==1){
      const float v0 = Vc[m.uvV + k2] * rh0c;
      const float v1 = Vc[m.uvV + m.dp4 + k2] * rh0c;
      const float2* Up = reinterpret_cast<const float2*>(Ush_v + m.uvU);   // [d][2]
      #pragma unroll
      for (int k1=0;k1<d;k1++){
        const float2 u = Up[k1];                  // wave-uniform LDS broadcast
        za[k1] += u.x*v0 + u.y*v1;
      }
    } else {
      const float v0 = Vc[m.uvV + k2];
      const float v1 = Vc[m.uvV + m.dp4 + k2];
      const float v2 = Vc[m.uvV + 2*m.dp4 + k2];
      const float v3 = Vc[m.uvV + 3*m.dp4 + k2];
      const float4* Up = reinterpret_cast<const float4*>(Ush_v + m.uvU);   // [d][4]
      #pragma unroll
      for (int k1=0;k1<d;k1++){
        const float4 u = Up[k1];                  // wave-uniform LDS broadcast, 16B-aligned
        za[k1] += u.x*v0 + u.y*v1 + u.z*v2 + u.w*v3;
      }
    }
  }
  float s = 0.f;
  #pragma unroll
  for (int k1=0;k1<d;k1++){
    zsh[zb + k1*d + k2] = za[k1];   // LDS scatter (d odd -> conflict-light); global is ph3b
    s += za[k1]*za[k1];
  }
  return s;
}

// one li-pure pass for one voxel: lane -> (c,k2) column within [base,end)
template<int LI>
__device__ __forceinline__ void do_passv(int base, int end, int lane, int v,
    const float* __restrict__ Vab, const float* Ush, const float* rh0s,
    float* zsh, float* fpart, float c000)
{
  constexpr int d = 4*LI + 1;
  const int col = base + lane;
  if (col >= end) return;
  const int c  = col / d;               // constexpr d -> magic mul
  const int k2 = col - c*d;
  const float s = col_work<LI>(k2, rh0s[v*8+c], c000, Vab + c*UVS, Ush + v*UVSU,
                               zsh, ZB[LI] + c*d*d);
  fpart[CBASE[LI] + col] = s;
}

// ---------------- kernel 2: main, one block per 2 voxels, 5 blocks/CU (LDS 32288B) ------------
// __launch_bounds__(256,4) keeps the allocator's natural 64-VGPR target (no squeeze — the
// R6 regression was bounds(256,5)->48 VGPR spills); 64 <= 102-VGPR budget at 20 waves/CU,
// so the LDS diet alone buys the 5th block.
__global__ __launch_bounds__(WGB,4) void s2_main(
    const float* __restrict__ x0, const float* __restrict__ x2, const float* __restrict__ x4,
    const float* __restrict__ x6, const float* __restrict__ x8,
    const float* __restrict__ w0, const float* __restrict__ bias,
    const float* __restrict__ cg, const int4* __restrict__ wiU,
    const float* __restrict__ V, float* __restrict__ out, float c000)
{
  __shared__ alignas(16) float SH[SHTOT];
  float* const xb    = SH;             // aliases z head; dead before first z write (barrier between)
  float* const Ush   = SH + UOFF;
  float* const rh0s  = SH + ROFF;
  float* const fpart = SH + FOFF;
  const int tid = threadIdx.x;
  const int bid = blockIdx.x;
  const int ab  = bid >> 9;            // vox = bid*2+v; both voxels share ab

  // ---- phase 0: stage x for 2 voxels (half-block each), compute rh0 ----
  {
    const int v  = tid >> 7;           // 0 or 1
    const int t2 = tid & 127;
    const int vox = bid*2 + v;
    float* xv = xb + v*XBS;
    if (t2 < 5)        xv[t2]           = x0[vox*5  + t2];
    else if (t2 < 15)  xv[8  + (t2-5)]  = x2[vox*10 + (t2-5)];
    else if (t2 < 33)  xv[18 + (t2-15)] = x4[vox*18 + (t2-15)];
    else if (t2 < 59)  xv[36 + (t2-33)] = x6[vox*26 + (t2-33)];
    else if (t2 < 93)  xv[62 + (t2-59)] = x8[vox*34 + (t2-59)];
    else if (t2 >= 96 && t2 < 104) {
      const int c = t2 - 96;
      float s = bias[ab*8 + c];
      for (int i=0;i<5;i++) s += x0[vox*5+i] * w0[(ab*5+i)*8 + c];
      rh0s[v*8 + c] = s;
    }
  }
  __syncthreads();

  // ---- phase 1+2 fused: d1-pure LPT-balanced wave passes (2 per wave) ----
  #pragma unroll 1
  for (int it=0; it<2; it++) u_item(wiU[it*WGB + tid], cg, xb, Ush);
  __syncthreads();                     // after this barrier xb is dead; z may be written

  // ---- phases 3/3b/4 per voxel, z buffer reused ----
  const float* Vab = V + (ab*8)*UVS;
  const int wid = tid>>6, lane = tid&63;
  #pragma unroll 1
  for (int v=0; v<2; v++){
    const int bid2 = bid*2 + v;
    #pragma unroll 1
    for (int pi=0; pi<3; pi++){
      const int li = SCHEDV[wid][pi][0];
      if (li < 0) break;
      const int base = SCHEDV[wid][pi][1], end = SCHEDV[wid][pi][2];
      switch(li){
        case 4:  do_passv<4>(base,end,lane,v,Vab,Ush,rh0s,SH,fpart,c000); break;
        case 3:  do_passv<3>(base,end,lane,v,Vab,Ush,rh0s,SH,fpart,c000); break;
        case 2:  do_passv<2>(base,end,lane,v,Vab,Ush,rh0s,SH,fpart,c000); break;
        case 1:  do_passv<1>(base,end,lane,v,Vab,Ush,rh0s,SH,fpart,c000); break;
        default: do_passv<0>(base,end,lane,v,Vab,Ush,rh0s,SH,fpart,c000); break;
      }
    }
    __syncthreads();

    // phase 3b: coalesced vf4 nt copy LDS z -> global rh_n (full lines per wave instruction:
    // the ONLY safe nt-store shape — partial-line nt/direct scatter cost 5-18x HBM, R1/R3)
    for (int i4 = tid; i4 < 1130; i4 += WGB){
      int li;
      if      (i4 < C4[1]) li = 0;
      else if (i4 < C4[2]) li = 1;
      else if (i4 < C4[3]) li = 2;
      else if (i4 < C4[4]) li = 3;
      else                 li = 4;
      const int r4 = i4 - C4[li];
      const vf4 zv = *reinterpret_cast<const vf4*>(SH + ZB[li] + 4*r4);
      __builtin_nontemporal_store(zv, reinterpret_cast<vf4*>(out + RHNB[li] + bid2*LEN5[li] + 4*r4));
    }

    // phase 4: feats reduce: n_l * sum z^2, layout (A,B, 5*N*C)
    if (tid < 40){
      const int li = tid >> 3, c = tid & 7;
      const int d = DL[li];
      float s = 0.f;
      for (int k2=0;k2<d;k2++) s += fpart[CBASE[li] + c*d + k2];
      const double nl_d = 8.0*3.14159265358979323846*3.14159265358979323846/(double)(2*(2*li)+1);
      const int n = bid2 & 1023;
      __builtin_nontemporal_store((float)nl_d * s, out + ab*40960 + li*8192 + n*8 + c);
    }
    if (v==0) __syncthreads();   // protect z/fpart before next voxel overwrites
  }
}

// ---------------- host: numpy MT19937 + legacy gauss, tables + CG upload at dlopen ----------------
namespace {

struct MTRng {
  uint32_t mt[624]; int mti;
  bool has_g; double g;
  void seed(uint32_t s){
    for (int pos=0; pos<624; pos++){ mt[pos]=s; s = 1812433253u*(s^(s>>30)) + (uint32_t)pos + 1u; }
    mti = 624; has_g=false; g=0.0;
  }
  uint32_t next32(){
    if (mti >= 624){
      for (int i=0;i<624;i++){
        uint32_t y = (mt[i]&0x80000000u) | (mt[(i+1)%624]&0x7fffffffu);
        mt[i] = mt[(i+397)%624] ^ (y>>1) ^ ((y&1u) ? 0x9908b0dfu : 0u);
      }
      mti = 0;
    }
    uint32_t y = mt[mti++];
    y ^= y>>11; y ^= (y<<7)&0x9d2c5680u; y ^= (y<<15)&0xefc60000u; y ^= y>>18;
    return y;
  }
  double rk_double(){
    uint32_t a = next32()>>5, b = next32()>>6;
    return (a*67108864.0 + b)/9007199254740992.0;
  }
  double gauss(){
    if (has_g){ has_g=false; return g; }
    double f,x1,x2,r2;
    do {
      x1 = 2.0*rk_double()-1.0;
      x2 = 2.0*rk_double()-1.0;
      r2 = x1*x1 + x2*x2;
    } while (r2 >= 1.0 || r2 == 0.0);
    f = std::sqrt(-2.0*std::log(r2)/r2);
    g = f*x1; has_g = true;
    return f*x2;
  }
};

constexpr int XOFS_H[5] = {0,8,18,36,62};

struct DeviceSetup {
  float* d_cg  = nullptr;   // [CG_R | CG_L]  (2*CG_TOTAL floats)
  float* d_v   = nullptr;   // 32 * UVS floats, rewritten by s2_prep every launch
  int4*  d_wiU = nullptr;   // WI_N padded items
  float  c000  = 0.f;
  DeviceSetup(){
    // CG tables, bit-faithful numpy RandomState(42)
    std::vector<float> h(2*CG_TOTAL);
    MTRng r; r.seed(42u);
    for (int i=0;i<2*CG_TOTAL;i++) h[i] = (float)(r.gauss()*0.1);
    c000 = h[META_H.t[0].cgL] * h[META_H.t[0].cgR];

    // fused U work items, grouped by d1 (wave-pure passes), d2-desc within group.
    // U destinations use the k1-major/pr-minor layout: dst = uvU + k1*npr, stride 1. (R6-proven)
    struct HItem { int d2; int4 e; };
    std::vector<HItem> grp[5];   // 0..3: FormA d1=5/9/13/17 ; 4: FormB
    for (int t=0;t<META_H.nT;t++){
      const TripleMeta &m = META_H.t[t];
      if (m.form==0){
        const int xo1 = XOFS_H[m.l1>>1], xo2 = XOFS_H[m.l2>>1];
        for (int k1=0;k1<m.d;k1++){
          int4 e;
          e.x = m.cgL + k1*m.d1*m.d2;
          e.y = (m.uvU + k1*4) | (1<<16);
          e.z = xo1 | (xo2<<8) | (m.d1<<16) | (m.d2<<22);
          e.w = 0;
          grp[(m.l1>>1)-1].push_back({m.d2, e});
        }
      } else if (m.form==1){
        const int xo2 = XOFS_H[m.l2>>1];
        for (int k1=0;k1<m.d;k1++){
          int4 e;
          e.x = m.cgL + k1*m.d2;
          e.y = (m.uvU + k1*2) | (1<<16);
          e.z = (xo2<<8) | (0<<16) | (m.d2<<22);
          e.w = 0;
          grp[4].push_back({m.d2, e});
        }
      }
    }
    if (grp[0].size()!=111 || grp[1].size()!=128 || grp[2].size()!=89 ||
        grp[3].size()!=45  || grp[4].size()!=44) std::abort();
    for (int g=0; g<5; g++)
      std::stable_sort(grp[g].begin(), grp[g].end(),
                       [](const HItem&a, const HItem&b){ return a.d2 > b.d2; });

    // LPT layout onto 8 wave-passes (iter*256 + wave*64 + lane), sentinel {0,0,0,0}:
    // iter0: w0=d1x17(45)  w1=d1x13[0:64]  w2=d1x13[64:89]  w3=d1x9[0:64]
    // iter1: w0=FormB(44)  w1=d1x5[64:111] w2=d1x9[64:128]  w3=d1x5[0:64]
    // wave issue-cost: 1360 / 1384 / 1352 / 1224 (ideal 1330)
    int4 zero; zero.x=0; zero.y=0; zero.z=0; zero.w=0;
    std::vector<int4> wiU(WI_N, zero);
    auto place = [&](int iter, int w, const std::vector<HItem>& g, int s, int n){
      for (int i=0;i<n;i++) wiU[iter*256 + w*64 + i] = g[s+i].e;
    };
    place(0,0,grp[3],0,45);
    place(0,1,grp[2],0,64);
    place(0,2,grp[2],64,25);
    place(0,3,grp[1],0,64);
    place(1,0,grp[4],0,44);
    place(1,1,grp[0],64,47);
    place(1,2,grp[1],64,64);
    place(1,3,grp[0],0,64);

    (void)hipMalloc((void**)&d_cg,  sizeof(float)*2*CG_TOTAL);
    (void)hipMalloc((void**)&d_v,   sizeof(float)*32*UVS);
    (void)hipMalloc((void**)&d_wiU, sizeof(int4)*WI_N);
    (void)hipMemcpy(d_cg,  h.data(),    sizeof(float)*2*CG_TOTAL, hipMemcpyHostToDevice);
    (void)hipMemcpy(d_wiU, wiU.data(),  sizeof(int4)*WI_N,  hipMemcpyHostToDevice);
  }
};
DeviceSetup g_dev;   // static init at dlopen: pure-CPU RNG + one-time uploads (outside graph capture)

} // namespace

extern "C" void kernel_launch(void* const* d_in, const int* in_sizes, int n_in,
                              void* d_out, int out_size, void* d_ws, size_t ws_size,
                              hipStream_t stream)
{
  (void)in_sizes; (void)n_in; (void)d_ws; (void)ws_size; (void)out_size;
  const float* x0   = (const float*)d_in[0];
  const float* w0   = (const float*)d_in[1];
  const float* x2   = (const float*)d_in[2];
  const float* w2   = (const float*)d_in[3];
  const float* x4   = (const float*)d_in[4];
  const float* w4   = (const float*)d_in[5];
  const float* x6   = (const float*)d_in[6];
  const float* w6   = (const float*)d_in[7];
  const float* x8   = (const float*)d_in[8];
  const float* w8   = (const float*)d_in[9];
  const float* bias = (const float*)d_in[10];
  float* out = (float*)d_out;

  s2_prep<<<dim3(42*32), dim3(128), 0, stream>>>(w2,w4,w6,w8, g_dev.d_cg, g_dev.d_v);
  s2_main<<<dim3(2048), dim3(WGB), 0, stream>>>(x0,x2,x4,x6,x8, w0, bias,
                                                g_dev.d_cg, g_dev.d_wiU,
                                                g_dev.d_v, out, g_dev.c000);
}

// Round 14
// 215.989 us; speedup vs baseline: 1.2007x; 1.0547x over previous
//
#include <hip/hip_runtime.h>
#include <cmath>
#include <cstdint>
#include <vector>
#include <cstdlib>
#include <algorithm>

#define WGB 256

typedef float vf4 __attribute__((ext_vector_type(4)));   // native vector: OK for nontemporal builtins

// ---------------- constexpr problem metadata (evaluated identically host+device) ----------------
struct TripleMeta { int l,l1,l2,d,d1,d2,form,dp4,cgR,cgL,uvV,uvU; };
struct AllMeta { TripleMeta t[48]; int nT, cgTotal, uvTotal, uvUTotal; };

constexpr AllMeta build_meta() {
  AllMeta M{};
  const int LSl[5] = {0,2,4,6,8};
  int k=0, cg=0;
  for (int a=0;a<5;a++){ const int l=LSl[a];
    for (int b=0;b<5;b++){ const int l1=LSl[b];
      for (int l2=l1;l2<=8;l2+=2){
        if (!((l2-l1)<=l && l<=(l1+l2))) continue;
        TripleMeta m{};
        m.l=l; m.l1=l1; m.l2=l2;
        m.d=2*l+1; m.d1=2*l1+1; m.d2=2*l2+1;
        m.form = (l1==0) ? ((l2==0)?2:1) : 0;   // 0=A (l1>0), 1=B (l1==0,l2>0), 2=D (0,0,0)
        m.dp4 = ((m.d+3)/4)*4;
        m.cgR = cg; cg += m.d*m.d1*m.d2;
        M.t[k] = m; k++;
      } } }
  M.nT=k; M.cgTotal=cg;
  int cgl=cg;
  for (int i=0;i<k;i++){ M.t[i].cgL=cgl; cgl += M.t[i].d*M.t[i].d1*M.t[i].d2; }
  int uv=0, uvu=0;
  for (int i=0;i<k;i++){
    // V table (GLOBAL, prep output): pq-major, dp4-padded — unchanged (k2-scalar reads).
    // U table (LDS): k1-major, pr-minor, PAD-FREE (R6/R13-proven). A: [d][4]; B: [d][2]+2 pad
    // -> every uvU stays %4==0 (A adds 4d; B adds 2d+2, d odd -> both %4==0): float4-aligned.
    if (M.t[i].form==0){ M.t[i].uvV=uv; uv += 4*M.t[i].dp4; M.t[i].uvU=uvu; uvu += 4*M.t[i].d; }
    else if (M.t[i].form==1){ M.t[i].uvV=uv; uv += 2*M.t[i].dp4; M.t[i].uvU=uvu; uvu += 2*M.t[i].d + 2; }
  }
  M.uvTotal=uv; M.uvUTotal=uvu;
  return M;
}

constexpr AllMeta META_H = build_meta();            // host view
static_assert(META_H.nT==42, "nT");
static_assert(META_H.cgTotal==52334, "cgTotal");
static_assert(META_H.uvTotal==2048, "uvTotal");
static_assert(META_H.uvUTotal==1588, "uvUTotal");

__device__ constexpr AllMeta META = build_meta();   // device view (identical values)

constexpr int CG_TOTAL  = 52334;
constexpr int UVS       = 2048;      // V slot-table stride in GLOBAL (floats, dp4-padded)
constexpr int UVSU      = 1588;      // packed U stride in LDS (k1-major; %4==0, 16B-aligned base)
constexpr int ZTOT      = 4520;      // z-buffer floats in LDS (8*d^2 summed, one voxel)
constexpr int XBS       = 104;       // per-voxel xb stride in LDS
constexpr int WI_N      = 512;       // padded U work-item table: 8 wave-passes x 64 lanes

// LDS layout (floats): z [0,4520) — xb[208] aliases its head (xb dead before first z write)
//                      U [4520,7696) | rh0s [7696,7712) | fpart [7712,7792) (atomicAdd, R4-form)
constexpr int UOFF  = 4520;
constexpr int ROFF  = UOFF + 2*UVSU;          // 7696
constexpr int FOFF  = ROFF + 16;              // 7712
constexpr int SHTOT = FOFF + 80;              // 7792 floats = 31168 B -> 5 blocks/CU headroom

__device__ constexpr int DL[5]     = {1,5,9,13,17};
__device__ constexpr int T0G[6]    = {0,5,13,23,33,42};       // triple ranges per output-l group
__device__ constexpr int RHNB[5]   = {163840,196608,1015808,3670016,9207808}; // rh_n out offsets
__device__ constexpr int LEN5[5]   = {8,200,648,1352,2312};   // 8*d^2 per voxel
// z-buffer: per-li base, 8*d^2 each; all %4==0 for float4 copy
__device__ constexpr int ZB[5]     = {0,8,208,856,2208};
__device__ constexpr int C4[6]     = {0,2,52,214,552,1130};   // cumulative float4 counts

// phase-3 static PER-VOXEL wave schedule: li-pure passes {li, col_base, col_end},
// col-space per li = 8c*d = {8,40,72,104,136}. Wave totals 1136/1136/988/1216 (ideal 1119).
__device__ constexpr int SCHEDV[4][3][3] = {
  {{4,  0, 46},{2,  0, 36},{-1,0,0}},
  {{4, 46, 91},{2, 36, 72},{-1,0,0}},
  {{4, 91,136},{1,  0, 40},{ 0,0,8}},
  {{3,  0, 52},{3, 52,104},{-1,0,0}},
};

// ---------------- kernel 1: V table — one block per (triple, abc), CG slab staged in LDS ----------------
// (R0's 1344-block form: measured rest ≈ 72-91us vs 138us for the 84-block variant)
// V_{t,p,q}[k2] = sum_a wA[p,a] * sum_j wB[q,j] * R_t[k2,a,j]
__global__ __launch_bounds__(128) void s2_prep(
    const float* __restrict__ w2, const float* __restrict__ w4,
    const float* __restrict__ w6, const float* __restrict__ w8,
    const float* __restrict__ cg, float* __restrict__ V)
{
  __shared__ float Rs[4928];           // max d*d1*d2 = 17*17*17 = 4913
  const int bid = blockIdx.x;
  const int t   = bid >> 5;
  const int abc = bid & 31;
  const auto &m = META.t[t];
  if (m.form == 2) return;             // (0,0,0) handled analytically in s2_main
  const int ab = abc >> 3, c = abc & 7;
  const int sz = m.d * m.d1 * m.d2;
  for (int i = threadIdx.x; i < sz; i += 128) Rs[i] = cg[m.cgR + i];   // coalesced
  __syncthreads();
  const float* ws[4] = {w2,w4,w6,w8};
  const int nout = (m.form==0 ? 4 : 2) * m.d;
  if ((int)threadIdx.x < nout){
    const int pq = threadIdx.x / m.d;
    const int k2 = threadIdx.x - pq*m.d;
    float s = 0.f;
    if (m.form==0){
      const int p = pq>>1, q = pq&1;
      const float* wA = ws[(m.l1>>1)-1] + ((ab*2+p)*8 + c)*m.d1;
      const float* wB = ws[(m.l2>>1)-1] + ((ab*2+q)*8 + c)*m.d2;
      const float* Rk = Rs + k2*m.d1*m.d2;
      for (int a=0;a<m.d1;a++){
        float t2 = 0.f;
        for (int j=0;j<m.d2;j++) t2 += wB[j]*Rk[a*m.d2+j];
        s += wA[a]*t2;
      }
    } else {
      const float* wB = ws[(m.l2>>1)-1] + ((ab*2+pq)*8 + c)*m.d2;
      const float* Rk = Rs + k2*m.d2;   // d1==1
      for (int j=0;j<m.d2;j++) s += wB[j]*Rk[j];
    }
    V[abc*UVS + m.uvV + pq*m.dp4 + k2] = s;
  }
}

// ---------------- fused phase 1+2, G=2 voxels: one (t,k1) item -> 8 (or 4) U values ----------------
// U destination is k1-major/pr-minor: dst = uvU + k1*npr, dstr = 1 (pr stride). (R6/R13-proven)
template<int D1>
__device__ __forceinline__ void u_itemA(const float* __restrict__ Lp, const float* xb,
    float* Ush, int dst, int dstr, int xo1, int xo2, int d2)
{
  float x0r[2*D1], x1r[2*D1];
  #pragma unroll
  for (int j=0;j<2*D1;j++){ x0r[j] = xb[xo1+j]; x1r[j] = xb[XBS+xo1+j]; }
  float a00=0.f,a01=0.f,a10=0.f,a11=0.f;
  float b00=0.f,b01=0.f,b10=0.f,b11=0.f;
  for (int b=0;b<d2;b++){
    float i00=0.f, i01=0.f, i10=0.f, i11=0.f;     // i{voxel}{p}
    const float* Lb = Lp + b*D1;                   // contiguous slab: 8 FMAs per CG load
    #pragma unroll
    for (int j=0;j<D1;j++){
      const float lv=Lb[j];
      i00+=lv*x0r[j]; i01+=lv*x0r[D1+j];
      i10+=lv*x1r[j]; i11+=lv*x1r[D1+j];
    }
    const float q00=xb[xo2+b],     q01=xb[xo2+d2+b];
    const float q10=xb[XBS+xo2+b], q11=xb[XBS+xo2+d2+b];
    a00+=q00*i00; a01+=q01*i00; a10+=q00*i01; a11+=q01*i01;
    b00+=q10*i10; b01+=q11*i10; b10+=q10*i11; b11+=q11*i11;
  }
  Ush[dst]=a00; Ush[dst+dstr]=a01; Ush[dst+2*dstr]=a10; Ush[dst+3*dstr]=a11;
  Ush[UVSU+dst]=b00; Ush[UVSU+dst+dstr]=b01; Ush[UVSU+dst+2*dstr]=b10; Ush[UVSU+dst+3*dstr]=b11;
}

__device__ __forceinline__ void u_item(const int4 w, const float* __restrict__ cg,
                                       const float* xb, float* Ush)
{
  if (w.z == 0) return;                 // idle-lane sentinel (real items have d2 field >= 5)
  const float* Lp = cg + w.x;
  const int dst = w.y & 0xFFFF, dstr = ((unsigned)w.y) >> 16;
  const int xo1 = w.z & 0xFF, xo2 = (w.z>>8)&0xFF;
  const int d1 = (w.z>>16)&0x3F, d2 = ((unsigned)w.z)>>22;
  if (d1 == 0){                         // FormB: U'[q][k1] = sum_b L[k1,b]*x2[q,b]
    float a0=0.f, a1=0.f, b0=0.f, b1=0.f;
    for (int b=0;b<d2;b++){
      const float lv=Lp[b];
      a0+=lv*xb[xo2+b];     a1+=lv*xb[xo2+d2+b];
      b0+=lv*xb[XBS+xo2+b]; b1+=lv*xb[XBS+xo2+d2+b];
    }
    Ush[dst]=a0; Ush[dst+dstr]=a1;
    Ush[UVSU+dst]=b0; Ush[UVSU+dst+dstr]=b1;
    return;
  }
  switch(d1){
    case 5:  u_itemA<5>(Lp,xb,Ush,dst,dstr,xo1,xo2,d2); break;
    case 9:  u_itemA<9>(Lp,xb,Ush,dst,dstr,xo1,xo2,d2); break;
    case 13: u_itemA<13>(Lp,xb,Ush,dst,dstr,xo1,xo2,d2); break;
    default: u_itemA<17>(Lp,xb,Ush,dst,dstr,xo1,xo2,d2); break;
  }
}

// ---------------- phase-3 column worker: lane owns (c,k2); k1 is the register axis -----------
// z(k1,k2) = sum_{t,pr} U[k1,pr] * V[pr,k2]. V = per-lane scalar global (L2, R2/R7-proven);
// U = wave-uniform float4/float2 LDS broadcast over the PAD-FREE k1-major layout (R13-proven:
// main 148->140us). z scattered to LDS; vf4 copy is ph3b.
template<int LI>
__device__ __forceinline__ float col_work(int k2, float rh0c, float c000,
    const float* __restrict__ Vc, const float* Ush_v,
    float* zsh, int zb)
{
  constexpr int d = 4*LI + 1;
  float za[d];
  #pragma unroll
  for (int i=0;i<d;i++) za[i] = 0.f;
  #pragma unroll
  for (int t=T0G[LI]; t<T0G[LI+1]; t++){
    const auto &m = META.t[t];
    if (m.form==2){
      za[0] += rh0c*rh0c*c000;
    } else if (m.form==1){
      const float v0 = Vc[m.uvV + k2] * rh0c;
      const float v1 = Vc[m.uvV + m.dp4 + k2] * rh0c;
      const float2* Up = reinterpret_cast<const float2*>(Ush_v + m.uvU);   // [d][2]
      #pragma unroll
      for (int k1=0;k1<d;k1++){
        const float2 u = Up[k1];                  // wave-uniform LDS broadcast
        za[k1] += u.x*v0 + u.y*v1;
      }
    } else {
      const float v0 = Vc[m.uvV + k2];
      const float v1 = Vc[m.uvV + m.dp4 + k2];
      const float v2 = Vc[m.uvV + 2*m.dp4 + k2];
      const float v3 = Vc[m.uvV + 3*m.dp4 + k2];
      const float4* Up = reinterpret_cast<const float4*>(Ush_v + m.uvU);   // [d][4]
      #pragma unroll
      for (int k1=0;k1<d;k1++){
        const float4 u = Up[k1];                  // wave-uniform LDS broadcast, 16B-aligned
        za[k1] += u.x*v0 + u.y*v1 + u.z*v2 + u.w*v3;
      }
    }
  }
  float s = 0.f;
  #pragma unroll
  for (int k1=0;k1<d;k1++){
    zsh[zb + k1*d + k2] = za[k1];   // LDS scatter (d odd -> conflict-light); global is ph3b
    s += za[k1]*za[k1];
  }
  return s;
}

// one li-pure pass for one voxel: lane -> (c,k2) column within [base,end)
template<int LI>
__device__ __forceinline__ void do_passv(int base, int end, int lane, int v,
    const float* __restrict__ Vab, const float* Ush, const float* rh0s,
    float* zsh, float* fpart, float c000)
{
  constexpr int d = 4*LI + 1;
  const int col = base + lane;
  if (col >= end) return;
  const int c  = col / d;               // constexpr d -> magic mul
  const int k2 = col - c*d;
  const float s = col_work<LI>(k2, rh0s[v*8+c], c000, Vab + c*UVS, Ush + v*UVSU,
                               zsh, ZB[LI] + c*d*d);
  atomicAdd(fpart + v*40 + LI*8 + c, s);   // <=17-way LDS collision, cheap (R4/R6-proven)
}

// ---------------- kernel 2: main, one block per 2 voxels, LDS 31168B -> 5 blocks/CU headroom --
// __launch_bounds__(256,4) keeps the allocator's natural 64-VGPR target (no squeeze).
__global__ __launch_bounds__(WGB,4) void s2_main(
    const float* __restrict__ x0, const float* __restrict__ x2, const float* __restrict__ x4,
    const float* __restrict__ x6, const float* __restrict__ x8,
    const float* __restrict__ w0, const float* __restrict__ bias,
    const float* __restrict__ cg, const int4* __restrict__ wiU,
    const float* __restrict__ V, float* __restrict__ out, float c000)
{
  __shared__ alignas(16) float SH[SHTOT];
  float* const xb    = SH;             // aliases z head; dead before first z write (barrier between)
  float* const Ush   = SH + UOFF;
  float* const rh0s  = SH + ROFF;
  float* const fpart = SH + FOFF;
  const int tid = threadIdx.x;
  const int bid = blockIdx.x;
  const int ab  = bid >> 9;            // vox = bid*2+v; both voxels share ab

  // ---- phase 0: stage x for 2 voxels (half-block each), compute rh0, zero fpart ----
  if (tid < 80) fpart[tid] = 0.f;
  {
    const int v  = tid >> 7;           // 0 or 1
    const int t2 = tid & 127;
    const int vox = bid*2 + v;
    float* xv = xb + v*XBS;
    if (t2 < 5)        xv[t2]           = x0[vox*5  + t2];
    else if (t2 < 15)  xv[8  + (t2-5)]  = x2[vox*10 + (t2-5)];
    else if (t2 < 33)  xv[18 + (t2-15)] = x4[vox*18 + (t2-15)];
    else if (t2 < 59)  xv[36 + (t2-33)] = x6[vox*26 + (t2-33)];
    else if (t2 < 93)  xv[62 + (t2-59)] = x8[vox*34 + (t2-59)];
    else if (t2 >= 96 && t2 < 104) {
      const int c = t2 - 96;
      float s = bias[ab*8 + c];
      for (int i=0;i<5;i++) s += x0[vox*5+i] * w0[(ab*5+i)*8 + c];
      rh0s[v*8 + c] = s;
    }
  }
  __syncthreads();

  // ---- phase 1+2 fused: d1-pure LPT-balanced wave passes (2 per wave) ----
  #pragma unroll 1
  for (int it=0; it<2; it++) u_item(wiU[it*WGB + tid], cg, xb, Ush);
  __syncthreads();                     // after this barrier xb is dead; z may be written

  // ---- phases 3/3b per voxel, z buffer reused ----
  const float* Vab = V + (ab*8)*UVS;
  const int wid = tid>>6, lane = tid&63;
  #pragma unroll 1
  for (int v=0; v<2; v++){
    const int bid2 = bid*2 + v;
    #pragma unroll 1
    for (int pi=0; pi<3; pi++){
      const int li = SCHEDV[wid][pi][0];
      if (li < 0) break;
      const int base = SCHEDV[wid][pi][1], end = SCHEDV[wid][pi][2];
      switch(li){
        case 4:  do_passv<4>(base,end,lane,v,Vab,Ush,rh0s,SH,fpart,c000); break;
        case 3:  do_passv<3>(base,end,lane,v,Vab,Ush,rh0s,SH,fpart,c000); break;
        case 2:  do_passv<2>(base,end,lane,v,Vab,Ush,rh0s,SH,fpart,c000); break;
        case 1:  do_passv<1>(base,end,lane,v,Vab,Ush,rh0s,SH,fpart,c000); break;
        default: do_passv<0>(base,end,lane,v,Vab,Ush,rh0s,SH,fpart,c000); break;
      }
    }
    __syncthreads();                   // z complete AND all fpart atomics for this voxel visible

    // phase 3b: coalesced vf4 nt copy LDS z -> global rh_n (full lines per wave instruction:
    // the ONLY safe nt-store shape — partial-line nt/direct scatter cost 5-18x HBM, R1/R3)
    for (int i4 = tid; i4 < 1130; i4 += WGB){
      int li;
      if      (i4 < C4[1]) li = 0;
      else if (i4 < C4[2]) li = 1;
      else if (i4 < C4[3]) li = 2;
      else if (i4 < C4[4]) li = 3;
      else                 li = 4;
      const int r4 = i4 - C4[li];
      const vf4 zv = *reinterpret_cast<const vf4*>(SH + ZB[li] + 4*r4);
      __builtin_nontemporal_store(zv, reinterpret_cast<vf4*>(out + RHNB[li] + bid2*LEN5[li] + 4*r4));
    }
    if (v==0) __syncthreads();   // protect z before next voxel overwrites
  }

  // ---- phase 4: feats reduce: n_l * fpart, layout (A,B, 5*N*C) ----
  // (v=1 atomics completed before the v=1 pre-copy barrier above — R4-verified ordering)
  if (tid < 80){
    const int v  = (tid >= 40) ? 1 : 0;
    const int r  = tid - v*40;
    const int li = r >> 3, c = r & 7;
    const double nl_d = 8.0*3.14159265358979323846*3.14159265358979323846/(double)(2*(2*li)+1);
    const int bid2 = bid*2 + v;
    const int n = bid2 & 1023;
    __builtin_nontemporal_store((float)nl_d * fpart[tid], out + ab*40960 + li*8192 + n*8 + c);
  }
}

// ---------------- host: numpy MT19937 + legacy gauss, tables + CG upload at dlopen ----------------
namespace {

struct MTRng {
  uint32_t mt[624]; int mti;
  bool has_g; double g;
  void seed(uint32_t s){
    for (int pos=0; pos<624; pos++){ mt[pos]=s; s = 1812433253u*(s^(s>>30)) + (uint32_t)pos + 1u; }
    mti = 624; has_g=false; g=0.0;
  }
  uint32_t next32(){
    if (mti >= 624){
      for (int i=0;i<624;i++){
        uint32_t y = (mt[i]&0x80000000u) | (mt[(i+1)%624]&0x7fffffffu);
        mt[i] = mt[(i+397)%624] ^ (y>>1) ^ ((y&1u) ? 0x9908b0dfu : 0u);
      }
      mti = 0;
    }
    uint32_t y = mt[mti++];
    y ^= y>>11; y ^= (y<<7)&0x9d2c5680u; y ^= (y<<15)&0xefc60000u; y ^= y>>18;
    return y;
  }
  double rk_double(){
    uint32_t a = next32()>>5, b = next32()>>6;
    return (a*67108864.0 + b)/9007199254740992.0;
  }
  double gauss(){
    if (has_g){ has_g=false; return g; }
    double f,x1,x2,r2;
    do {
      x1 = 2.0*rk_double()-1.0;
      x2 = 2.0*rk_double()-1.0;
      r2 = x1*x1 + x2*x2;
    } while (r2 >= 1.0 || r2 == 0.0);
    f = std::sqrt(-2.0*std::log(r2)/r2);
    g = f*x1; has_g = true;
    return f*x2;
  }
};

constexpr int XOFS_H[5] = {0,8,18,36,62};

struct DeviceSetup {
  float* d_cg  = nullptr;   // [CG_R | CG_L]  (2*CG_TOTAL floats)
  float* d_v   = nullptr;   // 32 * UVS floats, rewritten by s2_prep every launch
  int4*  d_wiU = nullptr;   // WI_N padded items
  float  c000  = 0.f;
  DeviceSetup(){
    // CG tables, bit-faithful numpy RandomState(42)
    std::vector<float> h(2*CG_TOTAL);
    MTRng r; r.seed(42u);
    for (int i=0;i<2*CG_TOTAL;i++) h[i] = (float)(r.gauss()*0.1);
    c000 = h[META_H.t[0].cgL] * h[META_H.t[0].cgR];

    // fused U work items, grouped by d1 (wave-pure passes), d2-desc within group.
    // U destinations use the k1-major/pr-minor layout: dst = uvU + k1*npr, stride 1.
    struct HItem { int d2; int4 e; };
    std::vector<HItem> grp[5];   // 0..3: FormA d1=5/9/13/17 ; 4: FormB
    for (int t=0;t<META_H.nT;t++){
      const TripleMeta &m = META_H.t[t];
      if (m.form==0){
        const int xo1 = XOFS_H[m.l1>>1], xo2 = XOFS_H[m.l2>>1];
        for (int k1=0;k1<m.d;k1++){
          int4 e;
          e.x = m.cgL + k1*m.d1*m.d2;
          e.y = (m.uvU + k1*4) | (1<<16);
          e.z = xo1 | (xo2<<8) | (m.d1<<16) | (m.d2<<22);
          e.w = 0;
          grp[(m.l1>>1)-1].push_back({m.d2, e});
        }
      } else if (m.form==1){
        const int xo2 = XOFS_H[m.l2>>1];
        for (int k1=0;k1<m.d;k1++){
          int4 e;
          e.x = m.cgL + k1*m.d2;
          e.y = (m.uvU + k1*2) | (1<<16);
          e.z = (xo2<<8) | (0<<16) | (m.d2<<22);
          e.w = 0;
          grp[4].push_back({m.d2, e});
        }
      }
    }
    if (grp[0].size()!=111 || grp[1].size()!=128 || grp[2].size()!=89 ||
        grp[3].size()!=45  || grp[4].size()!=44) std::abort();
    for (int g=0; g<5; g++)
      std::stable_sort(grp[g].begin(), grp[g].end(),
                       [](const HItem&a, const HItem&b){ return a.d2 > b.d2; });

    // LPT layout onto 8 wave-passes (iter*256 + wave*64 + lane), sentinel {0,0,0,0}:
    // iter0: w0=d1x17(45)  w1=d1x13[0:64]  w2=d1x13[64:89]  w3=d1x9[0:64]
    // iter1: w0=FormB(44)  w1=d1x5[64:111] w2=d1x9[64:128]  w3=d1x5[0:64]
    // wave issue-cost: 1360 / 1384 / 1352 / 1224 (ideal 1330)
    int4 zero; zero.x=0; zero.y=0; zero.z=0; zero.w=0;
    std::vector<int4> wiU(WI_N, zero);
    auto place = [&](int iter, int w, const std::vector<HItem>& g, int s, int n){
      for (int i=0;i<n;i++) wiU[iter*256 + w*64 + i] = g[s+i].e;
    };
    place(0,0,grp[3],0,45);
    place(0,1,grp[2],0,64);
    place(0,2,grp[2],64,25);
    place(0,3,grp[1],0,64);
    place(1,0,grp[4],0,44);
    place(1,1,grp[0],64,47);
    place(1,2,grp[1],64,64);
    place(1,3,grp[0],0,64);

    (void)hipMalloc((void**)&d_cg,  sizeof(float)*2*CG_TOTAL);
    (void)hipMalloc((void**)&d_v,   sizeof(float)*32*UVS);
    (void)hipMalloc((void**)&d_wiU, sizeof(int4)*WI_N);
    (void)hipMemcpy(d_cg,  h.data(),    sizeof(float)*2*CG_TOTAL, hipMemcpyHostToDevice);
    (void)hipMemcpy(d_wiU, wiU.data(),  sizeof(int4)*WI_N,  hipMemcpyHostToDevice);
  }
};
DeviceSetup g_dev;   // static init at dlopen: pure-CPU RNG + one-time uploads (outside graph capture)

} // namespace

extern "C" void kernel_launch(void* const* d_in, const int* in_sizes, int n_in,
                              void* d_out, int out_size, void* d_ws, size_t ws_size,
                              hipStream_t stream)
{
  (void)in_sizes; (void)n_in; (void)d_ws; (void)ws_size; (void)out_size;
  const float* x0   = (const float*)d_in[0];
  const float* w0   = (const float*)d_in[1];
  const float* x2   = (const float*)d_in[2];
  const float* w2   = (const float*)d_in[3];
  const float* x4   = (const float*)d_in[4];
  const float* w4   = (const float*)d_in[5];
  const float* x6   = (const float*)d_in[6];
  const float* w6   = (const float*)d_in[7];
  const float* x8   = (const float*)d_in[8];
  const float* w8   = (const float*)d_in[9];
  const float* bias = (const float*)d_in[10];
  float* out = (float*)d_out;

  s2_prep<<<dim3(42*32), dim3(128), 0, stream>>>(w2,w4,w6,w8, g_dev.d_cg, g_dev.d_v);
  s2_main<<<dim3(2048), dim3(WGB), 0, stream>>>(x0,x2,x4,x6,x8, w0, bias,
                                                g_dev.d_cg, g_dev.d_wiU,
                                                g_dev.d_v, out, g_dev.c000);
}